// Round 3
// baseline (15463.229 us; speedup 1.0000x reference)
//
#include <hip/hip_runtime.h>

__device__ __forceinline__ float gelu_f(float x) {
    return 0.5f * x * (1.0f + erff(x * 0.7071067811865475f));
}

// ------------------------------------------------------------------
// GEMM: C[M,N] = act( resid + A[M,K] @ W[K,N] + bias )   all fp32
// 64x64 tile, BK=16, 256 thr, 4x4 acc/thread.
// ------------------------------------------------------------------
__device__ __forceinline__ void fma44(float (&acc)[4][4], const float4 a, const float4 b) {
    acc[0][0] += a.x*b.x; acc[0][1] += a.x*b.y; acc[0][2] += a.x*b.z; acc[0][3] += a.x*b.w;
    acc[1][0] += a.y*b.x; acc[1][1] += a.y*b.y; acc[1][2] += a.y*b.z; acc[1][3] += a.y*b.w;
    acc[2][0] += a.z*b.x; acc[2][1] += a.z*b.y; acc[2][2] += a.z*b.z; acc[2][3] += a.z*b.w;
    acc[3][0] += a.w*b.x; acc[3][1] += a.w*b.y; acc[3][2] += a.w*b.z; acc[3][3] += a.w*b.w;
}

__launch_bounds__(256)
__global__ void gemm_f32(const float* __restrict__ A, const float* __restrict__ W,
                         const float* __restrict__ bias, const float* __restrict__ resid,
                         float* __restrict__ C, int M, int N, int K, int act)
{
    __shared__ float As[16][64];
    __shared__ float Ws[16][64];
    const int tid = threadIdx.x;
    const int tx = tid & 15, ty = tid >> 4;
    const int m0 = blockIdx.y << 6, n0 = blockIdx.x << 6;
    const int ar = tid >> 2, ak = (tid & 3) << 2;
    const int wr = tid >> 4, wc = (tid & 15) << 2;
    float acc[4][4] = {};
    const float* Ap = A + (size_t)(m0 + ar) * K + ak;
    const float* Wp = W + (size_t)wr * N + n0 + wc;
    for (int k0 = 0; k0 < K; k0 += 16) {
        float4 av = *(const float4*)(Ap + k0);
        As[ak+0][ar] = av.x; As[ak+1][ar] = av.y; As[ak+2][ar] = av.z; As[ak+3][ar] = av.w;
        float4 wv = *(const float4*)(Wp + (size_t)k0 * N);
        Ws[wr][wc+0] = wv.x; Ws[wr][wc+1] = wv.y; Ws[wr][wc+2] = wv.z; Ws[wr][wc+3] = wv.w;
        __syncthreads();
        #pragma unroll
        for (int kk = 0; kk < 16; ++kk) {
            float4 a = *(const float4*)&As[kk][ty << 2];
            float4 b = *(const float4*)&Ws[kk][tx << 2];
            fma44(acc, a, b);
        }
        __syncthreads();
    }
    #pragma unroll
    for (int i = 0; i < 4; ++i) {
        size_t m = m0 + (ty << 2) + i;
        #pragma unroll
        for (int j = 0; j < 4; ++j) {
            int n = n0 + (tx << 2) + j;
            float v = acc[i][j];
            if (bias)  v += bias[n];
            if (resid) v += resid[m * N + n];
            if (act)   v = gelu_f(v);
            C[m * N + n] = v;
        }
    }
}

// ------------------------------------------------------------------
// Batched NT GEMM: P[z][s][t] = sum_d Q[z,s,d]*K[z,t,d]   (1024x1024x512 fp32)
// ------------------------------------------------------------------
__launch_bounds__(256)
__global__ void gemm_qkT(const float* __restrict__ Q, const float* __restrict__ Km,
                         float* __restrict__ P)
{
    __shared__ float Qs[16][64];
    __shared__ float Ks[16][64];
    const int tid = threadIdx.x;
    const int tx = tid & 15, ty = tid >> 4;
    const int b = blockIdx.z;
    const int s0 = blockIdx.y << 6, t0 = blockIdx.x << 6;
    const int r = tid >> 2, ko = (tid & 3) << 2;
    const float* Qp = Q + ((size_t)b << 19) + (s0 + r) * 512 + ko;
    const float* Kp = Km + ((size_t)b << 19) + (t0 + r) * 512 + ko;
    float acc[4][4] = {};
    for (int k0 = 0; k0 < 512; k0 += 16) {
        float4 qv = *(const float4*)(Qp + k0);
        float4 kv = *(const float4*)(Kp + k0);
        Qs[ko+0][r] = qv.x; Qs[ko+1][r] = qv.y; Qs[ko+2][r] = qv.z; Qs[ko+3][r] = qv.w;
        Ks[ko+0][r] = kv.x; Ks[ko+1][r] = kv.y; Ks[ko+2][r] = kv.z; Ks[ko+3][r] = kv.w;
        __syncthreads();
        #pragma unroll
        for (int kk = 0; kk < 16; ++kk) {
            float4 a  = *(const float4*)&Qs[kk][ty << 2];
            float4 bb = *(const float4*)&Ks[kk][tx << 2];
            fma44(acc, a, bb);
        }
        __syncthreads();
    }
    float* Pp = P + ((size_t)b << 20);
    #pragma unroll
    for (int i = 0; i < 4; ++i)
        #pragma unroll
        for (int j = 0; j < 4; ++j)
            Pp[(s0 + (ty<<2) + i) * 1024 + t0 + (tx<<2) + j] = acc[i][j];
}

// Diagonal sums: PART[pb][chunk][tau] = sum_{s in chunk} P[pb][s][(s-tau)&1023]
__launch_bounds__(256)
__global__ void corr_diag(const float* __restrict__ P, float* __restrict__ PART)
{
    __shared__ float lc[1024];
    const int pb = blockIdx.y, chunk = blockIdx.x, tid = threadIdx.x;
    #pragma unroll
    for (int k = 0; k < 4; ++k) lc[tid + (k<<8)] = 0.f;
    __syncthreads();
    const float* Pb = P + ((size_t)pb << 20);
    for (int s = chunk << 5; s < (chunk << 5) + 32; ++s) {
        const float* row = Pb + (s << 10);
        #pragma unroll
        for (int k = 0; k < 4; ++k) {
            int t = tid + (k << 8);
            lc[(s - t) & 1023] += row[t];
        }
        __syncthreads();
    }
    float* dst = PART + ((size_t)pb << 15) + (chunk << 10);
    #pragma unroll
    for (int k = 0; k < 4; ++k) { int tau = tid + (k<<8); dst[tau] = lc[tau]; }
}

// CORR[pb][tau] = (1/512) * sum_ch PART[pb][ch][tau]
__launch_bounds__(256)
__global__ void corr_reduce(const float* __restrict__ PART, float* __restrict__ CORR)
{
    int idx = blockIdx.x * 256 + threadIdx.x;   // pb*1024 + tau
    int pb = idx >> 10, tau = idx & 1023;
    const float* pp = PART + ((size_t)pb << 15) + tau;
    float s = 0.f;
    #pragma unroll
    for (int ch = 0; ch < 32; ++ch) s += pp[ch << 10];
    CORR[idx] = s * (1.f / 512.f);
}

// top-6 + softmax per batch-in-group
__launch_bounds__(256)
__global__ void topk6(const float* __restrict__ CORR, int* __restrict__ DELAY,
                      float* __restrict__ WGT)
{
    __shared__ float v[1024];
    __shared__ float rv[256];
    __shared__ int   ri[256];
    __shared__ float wv[6];
    __shared__ int   wi[6];
    const int b = blockIdx.x, tid = threadIdx.x;
    #pragma unroll
    for (int k = 0; k < 4; ++k) { int tau = tid + (k<<8); v[tau] = CORR[b*1024 + tau]; }
    __syncthreads();
    for (int it = 0; it < 6; ++it) {
        float best = v[tid]; int bi = tid;
        #pragma unroll
        for (int k = 1; k < 4; ++k) {
            int i = tid + (k << 8);
            float xv = v[i];
            if (xv > best) { best = xv; bi = i; }
        }
        rv[tid] = best; ri[tid] = bi;
        __syncthreads();
        for (int s = 128; s > 0; s >>= 1) {
            if (tid < s) {
                if (rv[tid+s] > rv[tid] || (rv[tid+s] == rv[tid] && ri[tid+s] < ri[tid])) {
                    rv[tid] = rv[tid+s]; ri[tid] = ri[tid+s];
                }
            }
            __syncthreads();
        }
        if (tid == 0) { wv[it] = rv[0]; wi[it] = ri[0]; v[ri[0]] = -1e30f; }
        __syncthreads();
    }
    if (tid == 0) {
        float mx = wv[0], s = 0.f, e[6];
        #pragma unroll
        for (int i = 0; i < 6; ++i) { e[i] = expf(wv[i] - mx); s += e[i]; }
        #pragma unroll
        for (int i = 0; i < 6; ++i) { WGT[b*6+i] = e[i]/s; DELAY[b*6+i] = wi[i]; }
    }
}

// O[b,t,d] = sum_i w_i * V[b,(t+delay_i)&1023,d]   (float4 over d)
__launch_bounds__(256)
__global__ void gather6(const float* __restrict__ V, const int* __restrict__ DELAY,
                        const float* __restrict__ WGT, float* __restrict__ O)
{
    int idx = blockIdx.x * 256 + threadIdx.x;     // TG*128 threads
    int d4 = idx & 127, bt = idx >> 7, t = bt & 1023, b = bt >> 10;
    const float4* Vb = (const float4*)V + ((size_t)b << 17);
    float4 acc = {0.f,0.f,0.f,0.f};
    #pragma unroll
    for (int i = 0; i < 6; ++i) {
        int s = (t + DELAY[b*6+i]) & 1023;
        float w = WGT[b*6+i];
        float4 xv = Vb[(s << 7) + d4];
        acc.x += w*xv.x; acc.y += w*xv.y; acc.z += w*xv.z; acc.w += w*xv.w;
    }
    ((float4*)O)[idx] = acc;
}

// series_decomp on (TG,512): S = X - movmean25, T = movmean (optional)
__launch_bounds__(256)
__global__ void decomp512(const float* __restrict__ X, float* __restrict__ S,
                          float* __restrict__ T)
{
    int idx = blockIdx.x * 256 + threadIdx.x;     // TG*512
    int d = idx & 511, bt = idx >> 9, t = bt & 1023;
    int base = bt - t;
    const float* Xb = X + ((size_t)base << 9) + d;
    float s = 0.f;
    #pragma unroll
    for (int w = -12; w <= 12; ++w) {
        int tt = t + w; tt = tt < 0 ? 0 : (tt > 1023 ? 1023 : tt);
        s += Xb[tt << 9];
    }
    float m = s * (1.f / 25.f);
    S[idx] = X[idx] - m;
    if (T) T[idx] = m;
}

// per-token layernorm
__launch_bounds__(256)
__global__ void ln_rows(const float* __restrict__ X, const float* __restrict__ w,
                        const float* __restrict__ bias, float* __restrict__ Y)
{
    __shared__ float r1[256], r2[256];
    const int row = blockIdx.x, tid = threadIdx.x;
    const float* xr = X + (size_t)row * 512;
    float x0 = xr[tid], x1 = xr[tid + 256];
    r1[tid] = x0 + x1; r2[tid] = x0*x0 + x1*x1;
    __syncthreads();
    for (int s = 128; s > 0; s >>= 1) {
        if (tid < s) { r1[tid] += r1[tid+s]; r2[tid] += r2[tid+s]; }
        __syncthreads();
    }
    float mu = r1[0] * (1.f/512.f);
    float var = r2[0] * (1.f/512.f) - mu*mu;
    float rstd = rsqrtf(var + 1e-5f);
    float* yr = Y + (size_t)row * 512;
    yr[tid]       = (x0 - mu) * rstd * w[tid]     + bias[tid];
    yr[tid + 256] = (x1 - mu) * rstd * w[tid+256] + bias[tid+256];
}

__launch_bounds__(256)
__global__ void colmean(const float* __restrict__ Y, float* __restrict__ COL)
{
    int i = blockIdx.x * 256 + threadIdx.x;   // b*512+d (b local)
    int b = i >> 9, d = i & 511;
    const float* p = Y + ((size_t)b << 19) + d;
    float s = 0.f;
    for (int t = 0; t < 1024; ++t) s += p[t << 9];
    COL[i] = s * (1.f/1024.f);
}

__launch_bounds__(256)
__global__ void submean(const float* __restrict__ Y, const float* __restrict__ COL,
                        float* __restrict__ Z)
{
    int idx = blockIdx.x * 256 + threadIdx.x;
    int d = idx & 511, b = idx >> 19;
    Z[idx] = Y[idx] - COL[(b << 9) + d];
}

// embedding: circ conv3 on x (C=7) + mark @ Wtem
__launch_bounds__(256)
__global__ void embed_e(const float* __restrict__ x, const float* __restrict__ mark,
                        const float* __restrict__ Wtok, const float* __restrict__ Wtem,
                        float* __restrict__ out)
{
    int idx = blockIdx.x * 256 + threadIdx.x;
    int d = idx & 511, bt = idx >> 9, t = bt & 1023, b = bt >> 10;
    float acc = 0.f;
    #pragma unroll
    for (int j = 0; j < 3; ++j) {
        int tt = (t + 1023 + j) & 1023;
        const float* xr = x + (size_t)(b*1024 + tt)*7;
        #pragma unroll
        for (int c = 0; c < 7; ++c)
            acc += xr[c] * Wtok[(j*7+c)*512 + d];
    }
    const float* mr = mark + (size_t)bt*4;
    #pragma unroll
    for (int m = 0; m < 4; ++m) acc += mr[m] * Wtem[m*512 + d];
    out[idx] = acc;
}

__launch_bounds__(256)
__global__ void mean7(const float* __restrict__ x, float* __restrict__ M7)
{
    __shared__ float r[256];
    int bc = blockIdx.x, b = bc / 7, c = bc % 7, tid = threadIdx.x;
    float s = 0.f;
    for (int t = tid; t < 1024; t += 256) s += x[(size_t)(b*1024+t)*7 + c];
    r[tid] = s; __syncthreads();
    for (int st = 128; st > 0; st >>= 1) { if (tid < st) r[tid] += r[tid+st]; __syncthreads(); }
    if (tid == 0) M7[bc] = r[0] * (1.f/1024.f);
}

__launch_bounds__(256)
__global__ void decomp7(const float* __restrict__ x, const float* __restrict__ M7,
                        float* __restrict__ SEAS7, float* __restrict__ TREND7)
{
    int idx = blockIdx.x * 256 + threadIdx.x;  // TG*7
    int c = idx % 7, bt = idx / 7, t = bt & 1023, b = bt >> 10;
    if (t < 512) {
        int s0 = t + 512;
        float s = 0.f;
        #pragma unroll
        for (int w = -12; w <= 12; ++w) {
            int tt = s0 + w; tt = tt < 0 ? 0 : (tt > 1023 ? 1023 : tt);
            s += x[(size_t)(b*1024+tt)*7 + c];
        }
        float m = s * (1.f/25.f);
        SEAS7[idx] = x[(size_t)(b*1024+s0)*7 + c] - m;
        TREND7[idx] = m;
    } else {
        SEAS7[idx] = 0.f;
        TREND7[idx] = M7[b*7 + c];
    }
}

// TREND7 += circ_conv3(T (TG,512), dec_trend_W (3,512,7))
__launch_bounds__(256)
__global__ void trendconv_acc(const float* __restrict__ T, const float* __restrict__ W,
                              float* __restrict__ TREND7)
{
    int idx = blockIdx.x * 256 + threadIdx.x;  // TG*7
    int co = idx % 7, bt = idx / 7, t = bt & 1023;
    int base = bt - t;
    float acc = 0.f;
    for (int j = 0; j < 3; ++j) {
        int tt = (t + 1023 + j) & 1023;
        const float* r = T + ((size_t)(base + tt) << 9);
        const float* wj = W + j*512*7 + co;
        for (int c = 0; c < 512; ++c) acc += r[c] * wj[c*7];
    }
    TREND7[idx] += acc;
}

// out[b,tt,c] = TREND7[b,512+tt,c] + X[b,512+tt,:] @ projW[:,c] + projb[c]
__launch_bounds__(256)
__global__ void final_out(const float* __restrict__ X, const float* __restrict__ PW,
                          const float* __restrict__ PB, const float* __restrict__ TREND7,
                          float* __restrict__ out)
{
    int idx = blockIdx.x * 256 + threadIdx.x;  // G*512*7
    int c = idx % 7, btt = idx / 7, tt = btt & 511, b = btt >> 9;
    int t = tt + 512;
    float acc = PB[c] + TREND7[(size_t)(b*1024 + t)*7 + c];
    const float* xr = X + ((size_t)(b*1024 + t) << 9);
    for (int d = 0; d < 512; ++d) acc += xr[d] * PW[d*7 + c];
    out[idx] = acc;
}

__launch_bounds__(256)
__global__ void sentinel(float* __restrict__ out, int n)
{
    int i = blockIdx.x * 256 + threadIdx.x;
    if (i < n) out[i] = -54321.0f;
}

// ------------------------------------------------------------------
extern "C" void kernel_launch(void* const* d_in, const int* in_sizes, int n_in,
                              void* d_out, int out_size, void* d_ws, size_t ws_size,
                              hipStream_t stream)
{
    const float* x_enc      = (const float*)d_in[0];
    const float* x_mark_enc = (const float*)d_in[1];
    const float* x_mark_dec = (const float*)d_in[3];
    const float* W_enc_tok  = (const float*)d_in[4];
    const float* W_enc_tem  = (const float*)d_in[5];
    const float* W_dec_tok  = (const float*)d_in[6];
    const float* W_dec_tem  = (const float*)d_in[7];
    const float* enc_attn_W = (const float*)d_in[8];
    const float* enc_attn_b = (const float*)d_in[9];
    const float* enc_ff1    = (const float*)d_in[10];
    const float* enc_ff2    = (const float*)d_in[11];
    const float* enc_ln_w   = (const float*)d_in[12];
    const float* enc_ln_b   = (const float*)d_in[13];
    const float* dec_self_W = (const float*)d_in[14];
    const float* dec_self_b = (const float*)d_in[15];
    const float* dec_cross_W= (const float*)d_in[16];
    const float* dec_cross_b= (const float*)d_in[17];
    const float* dec_ff1    = (const float*)d_in[18];
    const float* dec_ff2    = (const float*)d_in[19];
    const float* dec_trend_W= (const float*)d_in[20];
    const float* dec_ln_w   = (const float*)d_in[21];
    const float* dec_ln_b   = (const float*)d_in[22];
    const float* proj_W     = (const float*)d_in[23];
    const float* proj_b     = (const float*)d_in[24];
    float* out = (float*)d_out;

    const size_t MB = 1u << 20;
    auto need = [&](int g) -> size_t {
        size_t act = (size_t)g * 2 * MB;           // one fp32 activation buffer
        size_t pb  = (g < 8) ? g : 8;
        size_t scratch = pb * 4 * MB;              // P fp32 subgroup / FFN mid fp32
        size_t part = pb * 32 * 1024 * 4;
        size_t misc = (size_t)g * (4096 + 2048 + 28 + 2*28672 + 64) * 4;
        return act * 5 + scratch + part + misc + 65536;
    };
    int G = 0;
    for (int g = 32; g >= 1; g >>= 1) if (need(g) <= ws_size) { G = g; break; }
    if (G == 0) {
        sentinel<<<(out_size + 255) / 256, 256, 0, stream>>>(out, out_size);
        return;
    }
    const int TG = G * 1024;
    const int PB = (G < 8) ? G : 8, NSUB = G / PB;
    const int MC = PB * 512;                       // FFN mid chunk rows (PB*512*2048*4 = PB*4MB)
    const int NCH = TG / MC;

    char* p = (char*)d_ws;
    auto carve = [&](size_t bytes) -> char* {
        char* r = p; p += (bytes + 255) & ~(size_t)255; return r;
    };
    const size_t ACTB = (size_t)TG * 512 * 4;
    float* XA   = (float*)carve(ACTB);
    float* Qb   = (float*)carve(ACTB);
    float* Kb   = (float*)carve(ACTB);
    float* Vb   = (float*)carve(ACTB);
    float* ENCb = (float*)carve(ACTB);
    float* SCR  = (float*)carve((size_t)PB * 4 * MB);
    float* PART  = (float*)carve((size_t)PB * 32 * 1024 * 4);
    float* CORR  = (float*)carve((size_t)G * 1024 * 4);
    float* COL   = (float*)carve((size_t)G * 512 * 4);
    float* M7    = (float*)carve((size_t)G * 7 * 4);
    float* SEAS7 = (float*)carve((size_t)G * 1024 * 7 * 4);
    float* TREND7= (float*)carve((size_t)G * 1024 * 7 * 4);
    float* WGT   = (float*)carve((size_t)G * 6 * 4);
    int*   DELAY = (int*)  carve((size_t)G * 6 * 4);

    for (int g0 = 0; g0 < 32; g0 += G) {
        const float* xe  = x_enc      + (size_t)g0 * 1024 * 7;
        const float* me  = x_mark_enc + (size_t)g0 * 1024 * 4;
        const float* md  = x_mark_dec + (size_t)g0 * 1024 * 4;
        float*       outg= out        + (size_t)g0 * 512 * 7;

        auto attn = [&](const float* Xq, const float* Xkv, const float* Wm, const float* bv,
                        float* dest) {
            dim3 gp(8, TG / 64);
            gemm_f32<<<gp,256,0,stream>>>(Xq,  Wm + 0*262144, bv + 0,    nullptr, Qb, TG, 512, 512, 0);
            gemm_f32<<<gp,256,0,stream>>>(Xkv, Wm + 1*262144, bv + 512,  nullptr, Kb, TG, 512, 512, 0);
            gemm_f32<<<gp,256,0,stream>>>(Xkv, Wm + 2*262144, bv + 1024, nullptr, Vb, TG, 512, 512, 0);
            for (int s = 0; s < NSUB; ++s) {
                const float* Qs = Qb + (size_t)s * PB * 1024 * 512;
                const float* Ks = Kb + (size_t)s * PB * 1024 * 512;
                gemm_qkT<<<dim3(16,16,PB),256,0,stream>>>(Qs, Ks, SCR);
                corr_diag<<<dim3(32,PB),256,0,stream>>>(SCR, PART);
                corr_reduce<<<4*PB,256,0,stream>>>(PART, CORR + (size_t)s * PB * 1024);
            }
            topk6<<<G,256,0,stream>>>(CORR, DELAY, WGT);
            gather6<<<TG/2,256,0,stream>>>(Vb, DELAY, WGT, Qb);   // Q dead; reuse
            gemm_f32<<<gp,256,0,stream>>>(Qb, Wm + 3*262144, bv + 1536, Xq, dest, TG, 512, 512, 0);
        };
        auto ffn = [&](const float* Xin, const float* f1, const float* f2, float* dest) {
            for (int c = 0; c < NCH; ++c) {
                const float* Ah = Xin + (size_t)c * MC * 512;
                gemm_f32<<<dim3(32, MC/64),256,0,stream>>>(Ah, f1, nullptr, nullptr,
                                                           SCR, MC, 2048, 512, 1);
                gemm_f32<<<dim3(8, MC/64),256,0,stream>>>(SCR, f2, nullptr, Ah,
                                                          dest + (size_t)c * MC * 512, MC, 512, 2048, 0);
            }
        };

        // ---------------- encoder ----------------
        embed_e<<<TG*2,256,0,stream>>>(xe, me, W_enc_tok, W_enc_tem, XA);
        for (int l = 0; l < 2; ++l) {
            attn(XA, XA, enc_attn_W + (size_t)l*4*262144, enc_attn_b + (size_t)l*4*512, Kb);
            decomp512<<<TG*2,256,0,stream>>>(Kb, XA, nullptr);
            ffn(XA, enc_ff1 + (size_t)l*1048576, enc_ff2 + (size_t)l*1048576, Kb);
            decomp512<<<TG*2,256,0,stream>>>(Kb, XA, nullptr);
        }
        ln_rows<<<TG,256,0,stream>>>(XA, enc_ln_w, enc_ln_b, Kb);
        colmean<<<G*2,256,0,stream>>>(Kb, COL);
        submean<<<TG*2,256,0,stream>>>(Kb, COL, ENCb);

        // ---------------- decoder prep ----------------
        mean7<<<G*7,256,0,stream>>>(xe, M7);
        decomp7<<<G*28,256,0,stream>>>(xe, M7, SEAS7, TREND7);
        embed_e<<<TG*2,256,0,stream>>>(SEAS7, md, W_dec_tok, W_dec_tem, XA);

        // ---------------- decoder layer ----------------
        attn(XA, XA, dec_self_W, dec_self_b, Kb);
        decomp512<<<TG*2,256,0,stream>>>(Kb, XA, Qb);
        trendconv_acc<<<G*28,256,0,stream>>>(Qb, dec_trend_W, TREND7);

        attn(XA, ENCb, dec_cross_W, dec_cross_b, Kb);
        decomp512<<<TG*2,256,0,stream>>>(Kb, XA, Qb);
        trendconv_acc<<<G*28,256,0,stream>>>(Qb, dec_trend_W, TREND7);

        ffn(XA, dec_ff1, dec_ff2, Kb);
        decomp512<<<TG*2,256,0,stream>>>(Kb, XA, Qb);
        trendconv_acc<<<G*28,256,0,stream>>>(Qb, dec_trend_W, TREND7);

        ln_rows<<<TG,256,0,stream>>>(XA, dec_ln_w, dec_ln_b, Kb);
        colmean<<<G*2,256,0,stream>>>(Kb, COL);
        submean<<<TG*2,256,0,stream>>>(Kb, COL, Qb);

        final_out<<<G*14,256,0,stream>>>(Qb, proj_W, proj_b, TREND7, outg);
    }
}

// Round 4
// 12722.482 us; speedup vs baseline: 1.2154x; 1.2154x over previous
//
#include <hip/hip_runtime.h>

typedef unsigned short ushortb;
typedef __attribute__((ext_vector_type(8))) short bf16x8;
typedef __attribute__((ext_vector_type(4))) float f32x4;

__device__ __forceinline__ float b2f(ushortb u) {
    union { unsigned int i; float f; } c; c.i = ((unsigned int)u) << 16; return c.f;
}
__device__ __forceinline__ ushortb f2b(float f) {
    union { float f; unsigned int i; } c; c.f = f;
    unsigned int r = c.i + 0x7FFFu + ((c.i >> 16) & 1u);
    return (ushortb)(r >> 16);
}
__device__ __forceinline__ float gelu_f(float x) {
    return 0.5f * x * (1.0f + erff(x * 0.7071067811865475f));
}

// ------------------------------------------------------------------
// Split-bf16 MFMA GEMM (NT): C[M,N] = act(resid + A@B^T + bias)
// A: Ah/Al [M,K] bf16 row-major. B: Bh/Bl [N,K] bf16 row-major.
// 3-term: AhBh + AlBh + AhBl (fp32-fidelity). 128x128 tile, BK=32,
// 256 thr (4 waves, 2x2 of 64x64), mfma_f32_16x16x32_bf16.
// Output: Cf fp32 and/or split (Ch,Cl). Batched via blockIdx.z strides.
// Requires M%128==0, N%128==0, K%32==0.
// ------------------------------------------------------------------
__launch_bounds__(256)
__global__ void gemm_sp(const ushortb* __restrict__ Ah, const ushortb* __restrict__ Al, long sA,
                        const ushortb* __restrict__ Bh, const ushortb* __restrict__ Bl, long sB,
                        const float* __restrict__ bias, const float* __restrict__ resid,
                        float* __restrict__ Cf, long sC,
                        ushortb* __restrict__ Ch, ushortb* __restrict__ Cl,
                        int M, int N, int K, int act)
{
    __shared__ ushortb LAh[128*40], LAl[128*40], LBh[128*40], LBl[128*40]; // pad 32->40
    const int tid  = threadIdx.x;
    const int lane = tid & 63, wave = tid >> 6;
    const int fr = lane & 15, fq = lane >> 4;
    const int m0 = blockIdx.y << 7, n0 = blockIdx.x << 7;
    const int wr = (wave & 1) << 6, wc = (wave >> 1) << 6;
    const size_t zb = blockIdx.z;
    Ah += zb * (size_t)sA; Al += zb * (size_t)sA;
    Bh += zb * (size_t)sB; Bl += zb * (size_t)sB;

    // staging: 512 16B-chunks per plane; thread handles chunks tid and tid+256
    const int c0 = tid, c1 = tid + 256;
    const int r0 = c0 >> 2, q0 = c0 & 3;
    const int r1 = c1 >> 2, q1 = c1 & 3;
    const size_t ga0 = (size_t)(m0 + r0) * K + q0 * 8;
    const size_t ga1 = (size_t)(m0 + r1) * K + q1 * 8;
    const size_t gb0 = (size_t)(n0 + r0) * K + q0 * 8;
    const size_t gb1 = (size_t)(n0 + r1) * K + q1 * 8;
    const int l0 = r0 * 40 + q0 * 8, l1 = r1 * 40 + q1 * 8;

    f32x4 acc[4][4] = {};

    for (int k0 = 0; k0 < K; k0 += 32) {
        uint4 vah0 = *(const uint4*)(Ah + ga0 + k0);
        uint4 vah1 = *(const uint4*)(Ah + ga1 + k0);
        uint4 val0 = *(const uint4*)(Al + ga0 + k0);
        uint4 val1 = *(const uint4*)(Al + ga1 + k0);
        uint4 vbh0 = *(const uint4*)(Bh + gb0 + k0);
        uint4 vbh1 = *(const uint4*)(Bh + gb1 + k0);
        uint4 vbl0 = *(const uint4*)(Bl + gb0 + k0);
        uint4 vbl1 = *(const uint4*)(Bl + gb1 + k0);
        __syncthreads();
        *(uint4*)(LAh + l0) = vah0; *(uint4*)(LAh + l1) = vah1;
        *(uint4*)(LAl + l0) = val0; *(uint4*)(LAl + l1) = val1;
        *(uint4*)(LBh + l0) = vbh0; *(uint4*)(LBh + l1) = vbh1;
        *(uint4*)(LBl + l0) = vbl0; *(uint4*)(LBl + l1) = vbl1;
        __syncthreads();
        bf16x8 afh[4], afl[4], bfh[4], bfl[4];
        #pragma unroll
        for (int t = 0; t < 4; ++t) {
            int ra = (wr + t*16 + fr) * 40 + fq * 8;
            int rb = (wc + t*16 + fr) * 40 + fq * 8;
            afh[t] = *(const bf16x8*)(const void*)(LAh + ra);
            afl[t] = *(const bf16x8*)(const void*)(LAl + ra);
            bfh[t] = *(const bf16x8*)(const void*)(LBh + rb);
            bfl[t] = *(const bf16x8*)(const void*)(LBl + rb);
        }
        #pragma unroll
        for (int tm = 0; tm < 4; ++tm)
            #pragma unroll
            for (int tn = 0; tn < 4; ++tn) {
                f32x4 c = acc[tm][tn];
                c = __builtin_amdgcn_mfma_f32_16x16x32_bf16(afh[tm], bfh[tn], c, 0, 0, 0);
                c = __builtin_amdgcn_mfma_f32_16x16x32_bf16(afl[tm], bfh[tn], c, 0, 0, 0);
                c = __builtin_amdgcn_mfma_f32_16x16x32_bf16(afh[tm], bfl[tn], c, 0, 0, 0);
                acc[tm][tn] = c;
            }
    }

    if (Cf) Cf += zb * (size_t)sC;
    if (Ch) { Ch += zb * (size_t)sC; Cl += zb * (size_t)sC; }
    #pragma unroll
    for (int tm = 0; tm < 4; ++tm) {
        #pragma unroll
        for (int tn = 0; tn < 4; ++tn) {
            int row0 = m0 + wr + tm*16 + fq*4;
            int col  = n0 + wc + tn*16 + fr;
            #pragma unroll
            for (int r = 0; r < 4; ++r) {
                float v = acc[tm][tn][r];
                size_t off = (size_t)(row0 + r) * N + col;
                if (bias)  v += bias[col];
                if (resid) v += resid[off];
                if (act)   v = gelu_f(v);
                if (Cf) Cf[off] = v;
                if (Ch) { ushortb h = f2b(v); Ch[off] = h; Cl[off] = f2b(v - b2f(h)); }
            }
        }
    }
}

// transpose + split weights: W [K,N] f32 -> Dh/Dl [N,K] bf16
__launch_bounds__(256)
__global__ void wsplit_t(const float* __restrict__ W, ushortb* __restrict__ Dh,
                         ushortb* __restrict__ Dl, int K, int N)
{
    int idx = blockIdx.x * 256 + threadIdx.x;
    if (idx >= K * N) return;
    int n = idx / K, k = idx - n * K;
    float v = W[(size_t)k * N + n];
    ushortb h = f2b(v);
    Dh[idx] = h; Dl[idx] = f2b(v - b2f(h));
}

// split fp32 -> bf16 hi/lo (4 elems/thread)
__launch_bounds__(256)
__global__ void split4(const float* __restrict__ X, ushortb* __restrict__ H,
                       ushortb* __restrict__ L, int n4)
{
    int i = blockIdx.x * 256 + threadIdx.x;
    if (i >= n4) return;
    float4 x = ((const float4*)X)[i];
    ushortb h0=f2b(x.x), h1=f2b(x.y), h2=f2b(x.z), h3=f2b(x.w);
    ushortb e0=f2b(x.x-b2f(h0)), e1=f2b(x.y-b2f(h1)), e2=f2b(x.z-b2f(h2)), e3=f2b(x.w-b2f(h3));
    uint2 hp, lp;
    hp.x = (unsigned)h0 | ((unsigned)h1<<16); hp.y = (unsigned)h2 | ((unsigned)h3<<16);
    lp.x = (unsigned)e0 | ((unsigned)e1<<16); lp.y = (unsigned)e2 | ((unsigned)e3<<16);
    ((uint2*)H)[i] = hp; ((uint2*)L)[i] = lp;
}

// Diagonal sums: PART[pb][chunk][tau] = sum_{s in chunk} P[pb][s][(s-tau)&1023]
__launch_bounds__(256)
__global__ void corr_diag(const float* __restrict__ P, float* __restrict__ PART)
{
    __shared__ float lc[1024];
    const int pb = blockIdx.y, chunk = blockIdx.x, tid = threadIdx.x;
    #pragma unroll
    for (int k = 0; k < 4; ++k) lc[tid + (k<<8)] = 0.f;
    __syncthreads();
    const float* Pb = P + ((size_t)pb << 20);
    for (int s = chunk << 5; s < (chunk << 5) + 32; ++s) {
        const float* row = Pb + (s << 10);
        #pragma unroll
        for (int k = 0; k < 4; ++k) {
            int t = tid + (k << 8);
            lc[(s - t) & 1023] += row[t];
        }
        __syncthreads();
    }
    float* dst = PART + ((size_t)pb << 15) + (chunk << 10);
    #pragma unroll
    for (int k = 0; k < 4; ++k) { int tau = tid + (k<<8); dst[tau] = lc[tau]; }
}

__launch_bounds__(256)
__global__ void corr_reduce(const float* __restrict__ PART, float* __restrict__ CORR)
{
    int idx = blockIdx.x * 256 + threadIdx.x;   // pb*1024 + tau
    int pb = idx >> 10, tau = idx & 1023;
    const float* pp = PART + ((size_t)pb << 15) + tau;
    float s = 0.f;
    #pragma unroll
    for (int ch = 0; ch < 32; ++ch) s += pp[ch << 10];
    CORR[idx] = s * (1.f / 512.f);
}

__launch_bounds__(256)
__global__ void topk6(const float* __restrict__ CORR, int* __restrict__ DELAY,
                      float* __restrict__ WGT)
{
    __shared__ float v[1024];
    __shared__ float rv[256];
    __shared__ int   ri[256];
    __shared__ float wv[6];
    __shared__ int   wi[6];
    const int b = blockIdx.x, tid = threadIdx.x;
    #pragma unroll
    for (int k = 0; k < 4; ++k) { int tau = tid + (k<<8); v[tau] = CORR[b*1024 + tau]; }
    __syncthreads();
    for (int it = 0; it < 6; ++it) {
        float best = v[tid]; int bi = tid;
        #pragma unroll
        for (int k = 1; k < 4; ++k) {
            int i = tid + (k << 8);
            float xv = v[i];
            if (xv > best) { best = xv; bi = i; }
        }
        rv[tid] = best; ri[tid] = bi;
        __syncthreads();
        for (int s = 128; s > 0; s >>= 1) {
            if (tid < s) {
                if (rv[tid+s] > rv[tid] || (rv[tid+s] == rv[tid] && ri[tid+s] < ri[tid])) {
                    rv[tid] = rv[tid+s]; ri[tid] = ri[tid+s];
                }
            }
            __syncthreads();
        }
        if (tid == 0) { wv[it] = rv[0]; wi[it] = ri[0]; v[ri[0]] = -1e30f; }
        __syncthreads();
    }
    if (tid == 0) {
        float mx = wv[0], s = 0.f, e[6];
        #pragma unroll
        for (int i = 0; i < 6; ++i) { e[i] = expf(wv[i] - mx); s += e[i]; }
        #pragma unroll
        for (int i = 0; i < 6; ++i) { WGT[b*6+i] = e[i]/s; DELAY[b*6+i] = wi[i]; }
    }
}

// O = sum_i w_i * V[b,(t+delay_i)&1023,:]  -> split bf16 output
__launch_bounds__(256)
__global__ void gather6s(const float* __restrict__ V, const int* __restrict__ DELAY,
                         const float* __restrict__ WGT, ushortb* __restrict__ Gh,
                         ushortb* __restrict__ Gl)
{
    int idx = blockIdx.x * 256 + threadIdx.x;     // TG*128 threads
    int d4 = idx & 127, bt = idx >> 7, t = bt & 1023, b = bt >> 10;
    const float4* Vb = (const float4*)V + ((size_t)b << 17);
    float4 acc = {0.f,0.f,0.f,0.f};
    #pragma unroll
    for (int i = 0; i < 6; ++i) {
        int s = (t + DELAY[b*6+i]) & 1023;
        float w = WGT[b*6+i];
        float4 xv = Vb[(s << 7) + d4];
        acc.x += w*xv.x; acc.y += w*xv.y; acc.z += w*xv.z; acc.w += w*xv.w;
    }
    ushortb h0=f2b(acc.x), h1=f2b(acc.y), h2=f2b(acc.z), h3=f2b(acc.w);
    ushortb e0=f2b(acc.x-b2f(h0)), e1=f2b(acc.y-b2f(h1)), e2=f2b(acc.z-b2f(h2)), e3=f2b(acc.w-b2f(h3));
    uint2 hp, lp;
    hp.x = (unsigned)h0 | ((unsigned)h1<<16); hp.y = (unsigned)h2 | ((unsigned)h3<<16);
    lp.x = (unsigned)e0 | ((unsigned)e1<<16); lp.y = (unsigned)e2 | ((unsigned)e3<<16);
    ((uint2*)Gh)[idx] = hp; ((uint2*)Gl)[idx] = lp;
}

// series_decomp on (TG,512): S = X - movmean25, T = movmean (optional)
__launch_bounds__(256)
__global__ void decomp512(const float* __restrict__ X, float* __restrict__ S,
                          float* __restrict__ T)
{
    int idx = blockIdx.x * 256 + threadIdx.x;     // TG*512
    int d = idx & 511, bt = idx >> 9, t = bt & 1023;
    int base = bt - t;
    const float* Xb = X + ((size_t)base << 9) + d;
    float s = 0.f;
    #pragma unroll
    for (int w = -12; w <= 12; ++w) {
        int tt = t + w; tt = tt < 0 ? 0 : (tt > 1023 ? 1023 : tt);
        s += Xb[tt << 9];
    }
    float m = s * (1.f / 25.f);
    S[idx] = X[idx] - m;
    if (T) T[idx] = m;
}

__launch_bounds__(256)
__global__ void ln_rows(const float* __restrict__ X, const float* __restrict__ w,
                        const float* __restrict__ bias, float* __restrict__ Y)
{
    __shared__ float r1[256], r2[256];
    const int row = blockIdx.x, tid = threadIdx.x;
    const float* xr = X + (size_t)row * 512;
    float x0 = xr[tid], x1 = xr[tid + 256];
    r1[tid] = x0 + x1; r2[tid] = x0*x0 + x1*x1;
    __syncthreads();
    for (int s = 128; s > 0; s >>= 1) {
        if (tid < s) { r1[tid] += r1[tid+s]; r2[tid] += r2[tid+s]; }
        __syncthreads();
    }
    float mu = r1[0] * (1.f/512.f);
    float var = r2[0] * (1.f/512.f) - mu*mu;
    float rstd = rsqrtf(var + 1e-5f);
    float* yr = Y + (size_t)row * 512;
    yr[tid]       = (x0 - mu) * rstd * w[tid]     + bias[tid];
    yr[tid + 256] = (x1 - mu) * rstd * w[tid+256] + bias[tid+256];
}

__launch_bounds__(256)
__global__ void colmean(const float* __restrict__ Y, float* __restrict__ COL)
{
    int i = blockIdx.x * 256 + threadIdx.x;
    int b = i >> 9, d = i & 511;
    const float* p = Y + ((size_t)b << 19) + d;
    float s = 0.f;
    for (int t = 0; t < 1024; ++t) s += p[t << 9];
    COL[i] = s * (1.f/1024.f);
}

__launch_bounds__(256)
__global__ void submean(const float* __restrict__ Y, const float* __restrict__ COL,
                        float* __restrict__ Z)
{
    int idx = blockIdx.x * 256 + threadIdx.x;
    int d = idx & 511, b = idx >> 19;
    Z[idx] = Y[idx] - COL[(b << 9) + d];
}

__launch_bounds__(256)
__global__ void embed_e(const float* __restrict__ x, const float* __restrict__ mark,
                        const float* __restrict__ Wtok, const float* __restrict__ Wtem,
                        float* __restrict__ out)
{
    int idx = blockIdx.x * 256 + threadIdx.x;
    int d = idx & 511, bt = idx >> 9, t = bt & 1023, b = bt >> 10;
    float acc = 0.f;
    #pragma unroll
    for (int j = 0; j < 3; ++j) {
        int tt = (t + 1023 + j) & 1023;
        const float* xr = x + (size_t)(b*1024 + tt)*7;
        #pragma unroll
        for (int c = 0; c < 7; ++c)
            acc += xr[c] * Wtok[(j*7+c)*512 + d];
    }
    const float* mr = mark + (size_t)bt*4;
    #pragma unroll
    for (int m = 0; m < 4; ++m) acc += mr[m] * Wtem[m*512 + d];
    out[idx] = acc;
}

__launch_bounds__(256)
__global__ void mean7(const float* __restrict__ x, float* __restrict__ M7)
{
    __shared__ float r[256];
    int bc = blockIdx.x, b = bc / 7, c = bc % 7, tid = threadIdx.x;
    float s = 0.f;
    for (int t = tid; t < 1024; t += 256) s += x[(size_t)(b*1024+t)*7 + c];
    r[tid] = s; __syncthreads();
    for (int st = 128; st > 0; st >>= 1) { if (tid < st) r[tid] += r[tid+st]; __syncthreads(); }
    if (tid == 0) M7[bc] = r[0] * (1.f/1024.f);
}

__launch_bounds__(256)
__global__ void decomp7(const float* __restrict__ x, const float* __restrict__ M7,
                        float* __restrict__ SEAS7, float* __restrict__ TREND7)
{
    int idx = blockIdx.x * 256 + threadIdx.x;  // TG*7
    int c = idx % 7, bt = idx / 7, t = bt & 1023, b = bt >> 10;
    if (t < 512) {
        int s0 = t + 512;
        float s = 0.f;
        #pragma unroll
        for (int w = -12; w <= 12; ++w) {
            int tt = s0 + w; tt = tt < 0 ? 0 : (tt > 1023 ? 1023 : tt);
            s += x[(size_t)(b*1024+tt)*7 + c];
        }
        float m = s * (1.f/25.f);
        SEAS7[idx] = x[(size_t)(b*1024+s0)*7 + c] - m;
        TREND7[idx] = m;
    } else {
        SEAS7[idx] = 0.f;
        TREND7[idx] = M7[b*7 + c];
    }
}

__launch_bounds__(256)
__global__ void trendconv_acc(const float* __restrict__ T, const float* __restrict__ W,
                              float* __restrict__ TREND7)
{
    int idx = blockIdx.x * 256 + threadIdx.x;  // TG*7
    int co = idx % 7, bt = idx / 7, t = bt & 1023;
    int base = bt - t;
    float acc = 0.f;
    for (int j = 0; j < 3; ++j) {
        int tt = (t + 1023 + j) & 1023;
        const float* r = T + ((size_t)(base + tt) << 9);
        const float* wj = W + j*512*7 + co;
        for (int c = 0; c < 512; ++c) acc += r[c] * wj[c*7];
    }
    TREND7[idx] += acc;
}

__launch_bounds__(256)
__global__ void final_out(const float* __restrict__ X, const float* __restrict__ PW,
                          const float* __restrict__ PB, const float* __restrict__ TREND7,
                          float* __restrict__ out)
{
    int idx = blockIdx.x * 256 + threadIdx.x;  // G*512*7
    int c = idx % 7, btt = idx / 7, tt = btt & 511, b = btt >> 9;
    int t = tt + 512;
    float acc = PB[c] + TREND7[(size_t)(b*1024 + t)*7 + c];
    const float* xr = X + ((size_t)(b*1024 + t) << 9);
    for (int d = 0; d < 512; ++d) acc += xr[d] * PW[d*7 + c];
    out[idx] = acc;
}

__launch_bounds__(256)
__global__ void sentinel(float* __restrict__ out, int n)
{
    int i = blockIdx.x * 256 + threadIdx.x;
    if (i < n) out[i] = -54321.0f;
}

// ------------------------------------------------------------------
extern "C" void kernel_launch(void* const* d_in, const int* in_sizes, int n_in,
                              void* d_out, int out_size, void* d_ws, size_t ws_size,
                              hipStream_t stream)
{
    const float* x_enc      = (const float*)d_in[0];
    const float* x_mark_enc = (const float*)d_in[1];
    const float* x_mark_dec = (const float*)d_in[3];
    const float* W_enc_tok  = (const float*)d_in[4];
    const float* W_enc_tem  = (const float*)d_in[5];
    const float* W_dec_tok  = (const float*)d_in[6];
    const float* W_dec_tem  = (const float*)d_in[7];
    const float* enc_attn_W = (const float*)d_in[8];
    const float* enc_attn_b = (const float*)d_in[9];
    const float* enc_ff1    = (const float*)d_in[10];
    const float* enc_ff2    = (const float*)d_in[11];
    const float* enc_ln_w   = (const float*)d_in[12];
    const float* enc_ln_b   = (const float*)d_in[13];
    const float* dec_self_W = (const float*)d_in[14];
    const float* dec_self_b = (const float*)d_in[15];
    const float* dec_cross_W= (const float*)d_in[16];
    const float* dec_cross_b= (const float*)d_in[17];
    const float* dec_ff1    = (const float*)d_in[18];
    const float* dec_ff2    = (const float*)d_in[19];
    const float* dec_trend_W= (const float*)d_in[20];
    const float* dec_ln_w   = (const float*)d_in[21];
    const float* dec_ln_b   = (const float*)d_in[22];
    const float* proj_W     = (const float*)d_in[23];
    const float* proj_b     = (const float*)d_in[24];
    float* out = (float*)d_out;

    // weight pool: 16 attn mats (512x512) + 3 ff1 (2048x512 T) + 3 ff2 (512x2048 T)
    const size_t ATT_B = (size_t)16 * 2 * 262144 * 2;   // 16.78 MB
    const size_t FF_B  = (size_t)3 * 2 * 1048576 * 2;   // 12.58 MB each
    const size_t WBYTES = ATT_B + 2 * FF_B + 4096;

    auto need = [&](int g) -> size_t {
        size_t TGl = (size_t)g * 1024;
        size_t fp32acts = 5 * TGl * 512 * 4;
        size_t splits   = 8 * TGl * 512 * 2;
        size_t pb = (g < 8) ? g : 8;
        size_t scr  = pb * 1024 * 1024 * 4;
        size_t part = pb * 32 * 1024 * 4;
        size_t misc = (size_t)g * (1024 + 512 + 7 + 2*7168 + 16) * 4 + 65536;
        return WBYTES + fp32acts + splits + scr + part + misc + 16384;
    };
    int G = 0;
    for (int g = 32; g >= 1; g >>= 1) if (need(g) <= ws_size) { G = g; break; }
    if (G == 0) {
        sentinel<<<(out_size + 255) / 256, 256, 0, stream>>>(out, out_size);
        return;
    }
    const int TG = G * 1024;
    const int PB = (G < 8) ? G : 8, NSUB = G / PB;
    const int MC = TG / 4;                       // FFN row chunk (MID fits split pool)

    char* p = (char*)d_ws;
    auto carve = [&](size_t bytes) -> char* {
        char* r = p; p += (bytes + 255) & ~(size_t)255; return r;
    };
    ushortb* ATT = (ushortb*)carve(ATT_B);     // mat m: hi at m*524288, lo +262144
    ushortb* FF1 = (ushortb*)carve(FF_B);      // mat i: hi at i*2097152, lo +1048576
    ushortb* FF2 = (ushortb*)carve(FF_B);

    const size_t ACTB = (size_t)TG * 512 * 4;
    const size_t SPLB = (size_t)TG * 512 * 2;
    float* XA   = (float*)carve(ACTB);
    float* Qb   = (float*)carve(ACTB);
    float* Kb   = (float*)carve(ACTB);
    float* Vb   = (float*)carve(ACTB);
    float* ENCb = (float*)carve(ACTB);
    ushortb* SAh = (ushortb*)carve(SPLB);
    ushortb* SAl = (ushortb*)carve(SPLB);
    ushortb* SEh = (ushortb*)carve(SPLB);
    ushortb* SEl = (ushortb*)carve(SPLB);
    ushortb* Qh  = (ushortb*)carve(SPLB);      // also gather output
    ushortb* Ql  = (ushortb*)carve(SPLB);
    ushortb* Kh  = (ushortb*)carve(SPLB);      // also FFN mid
    ushortb* Kl  = (ushortb*)carve(SPLB);
    float* SCR   = (float*)carve((size_t)PB * 1024 * 1024 * 4);
    float* PART  = (float*)carve((size_t)PB * 32 * 1024 * 4);
    float* CORR  = (float*)carve((size_t)G * 1024 * 4);
    float* COL   = (float*)carve((size_t)G * 512 * 4);
    float* M7    = (float*)carve((size_t)G * 7 * 4);
    float* SEAS7 = (float*)carve((size_t)G * 1024 * 7 * 4);
    float* TREND7= (float*)carve((size_t)G * 1024 * 7 * 4);
    float* WGT   = (float*)carve((size_t)G * 6 * 4);
    int*   DELAY = (int*)  carve((size_t)G * 6 * 4);

    // ---- weight transform (once per launch) ----
    for (int m = 0; m < 8; ++m)   // enc l0 (0-3), enc l1 (4-7)
        wsplit_t<<<1024,256,0,stream>>>(enc_attn_W + (size_t)m*262144,
                                        ATT + (size_t)m*524288, ATT + (size_t)m*524288 + 262144, 512, 512);
    for (int j = 0; j < 4; ++j)
        wsplit_t<<<1024,256,0,stream>>>(dec_self_W + (size_t)j*262144,
                                        ATT + (size_t)(8+j)*524288, ATT + (size_t)(8+j)*524288 + 262144, 512, 512);
    for (int j = 0; j < 4; ++j)
        wsplit_t<<<1024,256,0,stream>>>(dec_cross_W + (size_t)j*262144,
                                        ATT + (size_t)(12+j)*524288, ATT + (size_t)(12+j)*524288 + 262144, 512, 512);
    for (int l = 0; l < 2; ++l) {
        wsplit_t<<<4096,256,0,stream>>>(enc_ff1 + (size_t)l*1048576,
                                        FF1 + (size_t)l*2097152, FF1 + (size_t)l*2097152 + 1048576, 512, 2048);
        wsplit_t<<<4096,256,0,stream>>>(enc_ff2 + (size_t)l*1048576,
                                        FF2 + (size_t)l*2097152, FF2 + (size_t)l*2097152 + 1048576, 2048, 512);
    }
    wsplit_t<<<4096,256,0,stream>>>(dec_ff1, FF1 + (size_t)2*2097152, FF1 + (size_t)2*2097152 + 1048576, 512, 2048);
    wsplit_t<<<4096,256,0,stream>>>(dec_ff2, FF2 + (size_t)2*2097152, FF2 + (size_t)2*2097152 + 1048576, 2048, 512);

    for (int g0 = 0; g0 < 32; g0 += G) {
        const float* xe  = x_enc      + (size_t)g0 * 1024 * 7;
        const float* me  = x_mark_enc + (size_t)g0 * 1024 * 4;
        const float* md  = x_mark_dec + (size_t)g0 * 1024 * 4;
        float*       outg= out        + (size_t)g0 * 512 * 7;

        auto attn = [&](const float* Xq, const ushortb* kvh, const ushortb* kvl,
                        int mb, const float* bv, float* dest) {
            const ushortb* W0h = ATT + (size_t)(mb+0)*524288, *W0l = W0h + 262144;
            const ushortb* W1h = ATT + (size_t)(mb+1)*524288, *W1l = W1h + 262144;
            const ushortb* W2h = ATT + (size_t)(mb+2)*524288, *W2l = W2h + 262144;
            const ushortb* W3h = ATT + (size_t)(mb+3)*524288, *W3l = W3h + 262144;
            split4<<<TG/2,256,0,stream>>>(Xq, SAh, SAl, TG*128);
            dim3 gp(4, TG/128);
            gemm_sp<<<gp,256,0,stream>>>(SAh,SAl,0, W0h,W0l,0, bv+0,    nullptr, nullptr,0, Qh,Ql, TG,512,512,0);
            gemm_sp<<<gp,256,0,stream>>>(kvh,kvl,0, W1h,W1l,0, bv+512,  nullptr, nullptr,0, Kh,Kl, TG,512,512,0);
            gemm_sp<<<gp,256,0,stream>>>(kvh,kvl,0, W2h,W2l,0, bv+1024, nullptr, Vb,0, nullptr,nullptr, TG,512,512,0);
            for (int s = 0; s < NSUB; ++s) {
                size_t so = (size_t)s * PB * 524288;
                gemm_sp<<<dim3(8,8,PB),256,0,stream>>>(Qh+so,Ql+so,524288, Kh+so,Kl+so,524288,
                                                       nullptr, nullptr, SCR,1048576, nullptr,nullptr,
                                                       1024,1024,512,0);
                corr_diag<<<dim3(32,PB),256,0,stream>>>(SCR, PART);
                corr_reduce<<<4*PB,256,0,stream>>>(PART, CORR + (size_t)s * PB * 1024);
            }
            topk6<<<G,256,0,stream>>>(CORR, DELAY, WGT);
            gather6s<<<TG/2,256,0,stream>>>(Vb, DELAY, WGT, Qh, Ql);
            gemm_sp<<<gp,256,0,stream>>>(Qh,Ql,0, W3h,W3l,0, bv+1536, Xq, dest,0, nullptr,nullptr, TG,512,512,0);
        };
        auto ffn = [&](const float* Xin, int f1i, int f2i, float* dest) {
            const ushortb* F1h = FF1 + (size_t)f1i*2097152, *F1l = F1h + 1048576;
            const ushortb* F2h = FF2 + (size_t)f2i*2097152, *F2l = F2h + 1048576;
            split4<<<TG/2,256,0,stream>>>(Xin, SAh, SAl, TG*128);
            for (int c = 0; c < 4; ++c) {
                size_t ro = (size_t)c * MC * 512;
                gemm_sp<<<dim3(16, MC/128),256,0,stream>>>(SAh+ro,SAl+ro,0, F1h,F1l,0,
                                                           nullptr, nullptr, nullptr,0, Kh,Kl,
                                                           MC,2048,512,1);
                gemm_sp<<<dim3(4, MC/128),256,0,stream>>>(Kh,Kl,0, F2h,F2l,0,
                                                          nullptr, Xin+ro, dest+ro,0, nullptr,nullptr,
                                                          MC,512,2048,0);
            }
        };

        // ---------------- encoder ----------------
        embed_e<<<TG*2,256,0,stream>>>(xe, me, W_enc_tok, W_enc_tem, XA);
        for (int l = 0; l < 2; ++l) {
            attn(XA, SAh, SAl, l*4, enc_attn_b + (size_t)l*4*512, Kb);
            decomp512<<<TG*2,256,0,stream>>>(Kb, XA, nullptr);
            ffn(XA, l, l, Kb);
            decomp512<<<TG*2,256,0,stream>>>(Kb, XA, nullptr);
        }
        ln_rows<<<TG,256,0,stream>>>(XA, enc_ln_w, enc_ln_b, Kb);
        colmean<<<G*2,256,0,stream>>>(Kb, COL);
        submean<<<TG*2,256,0,stream>>>(Kb, COL, ENCb);
        split4<<<TG/2,256,0,stream>>>(ENCb, SEh, SEl, TG*128);

        // ---------------- decoder prep ----------------
        mean7<<<G*7,256,0,stream>>>(xe, M7);
        decomp7<<<G*28,256,0,stream>>>(xe, M7, SEAS7, TREND7);
        embed_e<<<TG*2,256,0,stream>>>(SEAS7, md, W_dec_tok, W_dec_tem, XA);

        // ---------------- decoder layer ----------------
        attn(XA, SAh, SAl, 8, dec_self_b, Kb);
        decomp512<<<TG*2,256,0,stream>>>(Kb, XA, Qb);
        trendconv_acc<<<G*28,256,0,stream>>>(Qb, dec_trend_W, TREND7);

        attn(XA, SEh, SEl, 12, dec_cross_b, Kb);
        decomp512<<<TG*2,256,0,stream>>>(Kb, XA, Qb);
        trendconv_acc<<<G*28,256,0,stream>>>(Qb, dec_trend_W, TREND7);

        ffn(XA, 2, 2, Kb);
        decomp512<<<TG*2,256,0,stream>>>(Kb, XA, Qb);
        trendconv_acc<<<G*28,256,0,stream>>>(Qb, dec_trend_W, TREND7);

        ln_rows<<<TG,256,0,stream>>>(XA, dec_ln_w, dec_ln_b, Kb);
        colmean<<<G*2,256,0,stream>>>(Kb, COL);
        submean<<<TG*2,256,0,stream>>>(Kb, COL, Qb);

        final_out<<<G*14,256,0,stream>>>(Qb, proj_W, proj_b, TREND7, outg);
    }
}

// Round 5
// 12159.141 us; speedup vs baseline: 1.2717x; 1.0463x over previous
//
#include <hip/hip_runtime.h>

typedef unsigned short ushortb;
typedef __attribute__((ext_vector_type(8))) short bf16x8;
typedef __attribute__((ext_vector_type(4))) float f32x4;

__device__ __forceinline__ float b2f(ushortb u) {
    union { unsigned int i; float f; } c; c.i = ((unsigned int)u) << 16; return c.f;
}
__device__ __forceinline__ ushortb f2b(float f) {
    union { float f; unsigned int i; } c; c.f = f;
    unsigned int r = c.i + 0x7FFFu + ((c.i >> 16) & 1u);
    return (ushortb)(r >> 16);
}
__device__ __forceinline__ float gelu_f(float x) {
    return 0.5f * x * (1.0f + erff(x * 0.7071067811865475f));
}

// async global->LDS, 16B per lane; LDS dest = wave-uniform base + lane*16
__device__ __forceinline__ void ld16(const void* g, void* l) {
    __builtin_amdgcn_global_load_lds(
        (const __attribute__((address_space(1))) unsigned int*)g,
        (__attribute__((address_space(3))) unsigned int*)l, 16, 0, 0);
}

// ------------------------------------------------------------------
// Split-bf16 MFMA GEMM (NT): C[M,N] = act(resid + A@B^T + bias)
// A: Ah/Al [M,K]; B: Bh/Bl [N,K] (bf16 hi/lo planes, row-major).
// 3-term AhBh+AlBh+AhBl = fp32 fidelity. 128x128 tile, BK=32, 256 thr.
// m97 recipe: unpadded [128][32] LDS planes + global_load_lds(16B).
// Requires M%128==0, N%128==0, K%32==0.
// ------------------------------------------------------------------
__launch_bounds__(256)
__global__ void gemm_sp(const ushortb* __restrict__ Ah, const ushortb* __restrict__ Al, long sA,
                        const ushortb* __restrict__ Bh, const ushortb* __restrict__ Bl, long sB,
                        const float* __restrict__ bias, const float* __restrict__ resid,
                        float* __restrict__ Cf, long sC,
                        ushortb* __restrict__ Ch, ushortb* __restrict__ Cl,
                        int M, int N, int K, int act)
{
    __shared__ __align__(16) ushortb LDS[16384];   // 4 planes x [128][32]
    const int tid = threadIdx.x;
    const int wv = tid >> 6, ln = tid & 63;
    const int fr = ln & 15, fq = ln >> 4;
    const int m0 = blockIdx.y << 7, n0 = blockIdx.x << 7;
    const int wr = (wv & 1) << 6, wc = (wv >> 1) << 6;
    const size_t zb = blockIdx.z;
    Ah += zb * (size_t)sA; Al += zb * (size_t)sA;
    Bh += zb * (size_t)sB; Bl += zb * (size_t)sB;

    // wave wv stages plane wv: 0=Ah 1=Al 2=Bh 3=Bl; 8 x 1KB segments
    const ushortb* gb = (wv == 0) ? Ah : (wv == 1) ? Al : (wv == 2) ? Bh : Bl;
    const int rbase = (wv < 2) ? m0 : n0;
    const ushortb* gp = gb + (size_t)(rbase + (ln >> 2)) * K + (ln & 3) * 8;
    ushortb* lplane = LDS + wv * 4096;
    const size_t rstep = (size_t)K << 4;   // 16 rows

    f32x4 acc[4][4] = {};

    for (int k0 = 0; k0 < K; k0 += 32) {
        __syncthreads();
        #pragma unroll
        for (int i = 0; i < 8; ++i)
            ld16(gp + (size_t)i * rstep, lplane + i * 512);
        gp += 32;
        __syncthreads();
        bf16x8 afh[4], afl[4], bfh[4], bfl[4];
        #pragma unroll
        for (int t = 0; t < 4; ++t) {
            int ra = ((wr + t*16 + fr) << 5) + (fq << 3);
            int rb = ((wc + t*16 + fr) << 5) + (fq << 3);
            afh[t] = *(const bf16x8*)(const void*)(LDS + ra);
            afl[t] = *(const bf16x8*)(const void*)(LDS + 4096 + ra);
            bfh[t] = *(const bf16x8*)(const void*)(LDS + 8192 + rb);
            bfl[t] = *(const bf16x8*)(const void*)(LDS + 12288 + rb);
        }
        #pragma unroll
        for (int tm = 0; tm < 4; ++tm)
            #pragma unroll
            for (int tn = 0; tn < 4; ++tn) {
                f32x4 c = acc[tm][tn];
                c = __builtin_amdgcn_mfma_f32_16x16x32_bf16(afh[tm], bfh[tn], c, 0, 0, 0);
                c = __builtin_amdgcn_mfma_f32_16x16x32_bf16(afl[tm], bfh[tn], c, 0, 0, 0);
                c = __builtin_amdgcn_mfma_f32_16x16x32_bf16(afh[tm], bfl[tn], c, 0, 0, 0);
                acc[tm][tn] = c;
            }
    }

    if (Cf) Cf += zb * (size_t)sC;
    if (Ch) { Ch += zb * (size_t)sC; Cl += zb * (size_t)sC; }
    #pragma unroll
    for (int tm = 0; tm < 4; ++tm) {
        #pragma unroll
        for (int tn = 0; tn < 4; ++tn) {
            int row0 = m0 + wr + tm*16 + fq*4;
            int col  = n0 + wc + tn*16 + fr;
            #pragma unroll
            for (int r = 0; r < 4; ++r) {
                float v = acc[tm][tn][r];
                size_t off = (size_t)(row0 + r) * N + col;
                if (bias)  v += bias[col];
                if (resid) v += resid[off];
                if (act)   v = gelu_f(v);
                if (Cf) Cf[off] = v;
                if (Ch) { ushortb h = f2b(v); Ch[off] = h; Cl[off] = f2b(v - b2f(h)); }
            }
        }
    }
}

// transpose + split weights: W [K,N] f32 -> Dh/Dl [N,K] bf16
__launch_bounds__(256)
__global__ void wsplit_t(const float* __restrict__ W, ushortb* __restrict__ Dh,
                         ushortb* __restrict__ Dl, int K, int N)
{
    int idx = blockIdx.x * 256 + threadIdx.x;
    if (idx >= K * N) return;
    int n = idx / K, k = idx - n * K;
    float v = W[(size_t)k * N + n];
    ushortb h = f2b(v);
    Dh[idx] = h; Dl[idx] = f2b(v - b2f(h));
}

// Diagonal sums: PART[pb][chunk][tau] = sum_{s in chunk} P[pb][s][(s-tau)&1023]
__launch_bounds__(256)
__global__ void corr_diag(const float* __restrict__ P, float* __restrict__ PART)
{
    __shared__ float lc[1024];
    const int pb = blockIdx.y, chunk = blockIdx.x, tid = threadIdx.x;
    #pragma unroll
    for (int k = 0; k < 4; ++k) lc[tid + (k<<8)] = 0.f;
    __syncthreads();
    const float* Pb = P + ((size_t)pb << 20);
    for (int s = chunk << 5; s < (chunk << 5) + 32; ++s) {
        const float* row = Pb + (s << 10);
        #pragma unroll
        for (int k = 0; k < 4; ++k) {
            int t = tid + (k << 8);
            lc[(s - t) & 1023] += row[t];
        }
        __syncthreads();
    }
    float* dst = PART + ((size_t)pb << 15) + (chunk << 10);
    #pragma unroll
    for (int k = 0; k < 4; ++k) { int tau = tid + (k<<8); dst[tau] = lc[tau]; }
}

// top-6 + softmax per local batch; reduces PART chunks inline
__launch_bounds__(256)
__global__ void topk6p(const float* __restrict__ PART, int* __restrict__ DELAY,
                       float* __restrict__ WGT)
{
    __shared__ float v[1024];
    __shared__ float rv[256];
    __shared__ int   ri[256];
    __shared__ float wv6[6];
    __shared__ int   wi6[6];
    const int b = blockIdx.x, tid = threadIdx.x;
    #pragma unroll
    for (int k = 0; k < 4; ++k) {
        int tau = tid + (k << 8);
        const float* pp = PART + ((size_t)b << 15) + tau;
        float s = 0.f;
        #pragma unroll
        for (int ch = 0; ch < 32; ++ch) s += pp[ch << 10];
        v[tau] = s * (1.f / 512.f);
    }
    __syncthreads();
    for (int it = 0; it < 6; ++it) {
        float best = v[tid]; int bi = tid;
        #pragma unroll
        for (int k = 1; k < 4; ++k) {
            int i = tid + (k << 8);
            float xv = v[i];
            if (xv > best) { best = xv; bi = i; }
        }
        rv[tid] = best; ri[tid] = bi;
        __syncthreads();
        for (int s = 128; s > 0; s >>= 1) {
            if (tid < s) {
                if (rv[tid+s] > rv[tid] || (rv[tid+s] == rv[tid] && ri[tid+s] < ri[tid])) {
                    rv[tid] = rv[tid+s]; ri[tid] = ri[tid+s];
                }
            }
            __syncthreads();
        }
        if (tid == 0) { wv6[it] = rv[0]; wi6[it] = ri[0]; v[ri[0]] = -1e30f; }
        __syncthreads();
    }
    if (tid == 0) {
        float mx = wv6[0], s = 0.f, e[6];
        #pragma unroll
        for (int i = 0; i < 6; ++i) { e[i] = expf(wv6[i] - mx); s += e[i]; }
        #pragma unroll
        for (int i = 0; i < 6; ++i) { WGT[b*6+i] = e[i]/s; DELAY[b*6+i] = wi6[i]; }
    }
}

// O = sum_i w_i * V[b,(t+delay_i)&1023,:]  -> split bf16 output
__launch_bounds__(256)
__global__ void gather6s(const float* __restrict__ V, const int* __restrict__ DELAY,
                         const float* __restrict__ WGT, ushortb* __restrict__ Gh,
                         ushortb* __restrict__ Gl)
{
    int idx = blockIdx.x * 256 + threadIdx.x;     // TG*128 threads
    int d4 = idx & 127, bt = idx >> 7, t = bt & 1023, b = bt >> 10;
    const float4* Vb = (const float4*)V + ((size_t)b << 17);
    float4 acc = {0.f,0.f,0.f,0.f};
    #pragma unroll
    for (int i = 0; i < 6; ++i) {
        int s = (t + DELAY[b*6+i]) & 1023;
        float w = WGT[b*6+i];
        float4 xv = Vb[(s << 7) + d4];
        acc.x += w*xv.x; acc.y += w*xv.y; acc.z += w*xv.z; acc.w += w*xv.w;
    }
    ushortb h0=f2b(acc.x), h1=f2b(acc.y), h2=f2b(acc.z), h3=f2b(acc.w);
    ushortb e0=f2b(acc.x-b2f(h0)), e1=f2b(acc.y-b2f(h1)), e2=f2b(acc.z-b2f(h2)), e3=f2b(acc.w-b2f(h3));
    uint2 hp, lp;
    hp.x = (unsigned)h0 | ((unsigned)h1<<16); hp.y = (unsigned)h2 | ((unsigned)h3<<16);
    lp.x = (unsigned)e0 | ((unsigned)e1<<16); lp.y = (unsigned)e2 | ((unsigned)e3<<16);
    ((uint2*)Gh)[idx] = hp; ((uint2*)Gl)[idx] = lp;
}

// series_decomp + fused split: S=X-movmean25 (fp32 + hi/lo), T=movmean optional
__launch_bounds__(256)
__global__ void decomp512s(const float* __restrict__ X, float* __restrict__ S,
                           ushortb* __restrict__ Sh, ushortb* __restrict__ Sl,
                           float* __restrict__ T)
{
    int idx = blockIdx.x * 256 + threadIdx.x;     // TG*512
    int d = idx & 511, bt = idx >> 9, t = bt & 1023;
    int base = bt - t;
    const float* Xb = X + ((size_t)base << 9) + d;
    float s = 0.f;
    #pragma unroll
    for (int w = -12; w <= 12; ++w) {
        int tt = t + w; tt = tt < 0 ? 0 : (tt > 1023 ? 1023 : tt);
        s += Xb[tt << 9];
    }
    float m = s * (1.f / 25.f);
    float v = X[idx] - m;
    S[idx] = v;
    ushortb h = f2b(v);
    Sh[idx] = h; Sl[idx] = f2b(v - b2f(h));
    if (T) T[idx] = m;
}

__launch_bounds__(256)
__global__ void ln_rows(const float* __restrict__ X, const float* __restrict__ w,
                        const float* __restrict__ bias, float* __restrict__ Y)
{
    __shared__ float r1[256], r2[256];
    const int row = blockIdx.x, tid = threadIdx.x;
    const float* xr = X + (size_t)row * 512;
    float x0 = xr[tid], x1 = xr[tid + 256];
    r1[tid] = x0 + x1; r2[tid] = x0*x0 + x1*x1;
    __syncthreads();
    for (int s = 128; s > 0; s >>= 1) {
        if (tid < s) { r1[tid] += r1[tid+s]; r2[tid] += r2[tid+s]; }
        __syncthreads();
    }
    float mu = r1[0] * (1.f/512.f);
    float var = r2[0] * (1.f/512.f) - mu*mu;
    float rstd = rsqrtf(var + 1e-5f);
    float* yr = Y + (size_t)row * 512;
    yr[tid]       = (x0 - mu) * rstd * w[tid]     + bias[tid];
    yr[tid + 256] = (x1 - mu) * rstd * w[tid+256] + bias[tid+256];
}

// column-mean partials: PC[b][d][c] = (1/1024) * sum_{t in chunk c} Y[b,t,d]
__launch_bounds__(256)
__global__ void colmean_p(const float* __restrict__ Y, float* __restrict__ PC)
{
    int i = blockIdx.x * 256 + threadIdx.x;   // G*4096
    int b = i >> 12, r = i & 4095, d = r >> 3, c = r & 7;
    const float* p = Y + ((size_t)b << 19) + ((size_t)(c << 7) << 9) + d;
    float s = 0.f;
    for (int t = 0; t < 128; ++t) s += p[t << 9];
    PC[i] = s * (1.f/1024.f);
}

// Z = Y - colmean (fp32 out and/or split out)
__launch_bounds__(256)
__global__ void submean_s(const float* __restrict__ Y, const float* __restrict__ PC,
                          float* __restrict__ Zf, ushortb* __restrict__ Zh,
                          ushortb* __restrict__ Zl)
{
    int idx = blockIdx.x * 256 + threadIdx.x;
    int d = idx & 511, b = idx >> 19;
    const float* pc = PC + ((size_t)b << 12) + (d << 3);
    float m = ((pc[0]+pc[1])+(pc[2]+pc[3]))+((pc[4]+pc[5])+(pc[6]+pc[7]));
    float v = Y[idx] - m;
    if (Zf) Zf[idx] = v;
    if (Zh) { ushortb h = f2b(v); Zh[idx] = h; Zl[idx] = f2b(v - b2f(h)); }
}

// embedding: circ conv3 (C=7) + mark @ Wtem, fused split
__launch_bounds__(256)
__global__ void embed_es(const float* __restrict__ x, const float* __restrict__ mark,
                         const float* __restrict__ Wtok, const float* __restrict__ Wtem,
                         float* __restrict__ out, ushortb* __restrict__ Oh,
                         ushortb* __restrict__ Ol)
{
    int idx = blockIdx.x * 256 + threadIdx.x;
    int d = idx & 511, bt = idx >> 9, t = bt & 1023, b = bt >> 10;
    float acc = 0.f;
    #pragma unroll
    for (int j = 0; j < 3; ++j) {
        int tt = (t + 1023 + j) & 1023;
        const float* xr = x + (size_t)(b*1024 + tt)*7;
        #pragma unroll
        for (int c = 0; c < 7; ++c)
            acc += xr[c] * Wtok[(j*7+c)*512 + d];
    }
    const float* mr = mark + (size_t)bt*4;
    #pragma unroll
    for (int m = 0; m < 4; ++m) acc += mr[m] * Wtem[m*512 + d];
    out[idx] = acc;
    ushortb h = f2b(acc);
    Oh[idx] = h; Ol[idx] = f2b(acc - b2f(h));
}

__launch_bounds__(256)
__global__ void mean7(const float* __restrict__ x, float* __restrict__ M7)
{
    __shared__ float r[256];
    int bc = blockIdx.x, b = bc / 7, c = bc % 7, tid = threadIdx.x;
    float s = 0.f;
    for (int t = tid; t < 1024; t += 256) s += x[(size_t)(b*1024+t)*7 + c];
    r[tid] = s; __syncthreads();
    for (int st = 128; st > 0; st >>= 1) { if (tid < st) r[tid] += r[tid+st]; __syncthreads(); }
    if (tid == 0) M7[bc] = r[0] * (1.f/1024.f);
}

__launch_bounds__(256)
__global__ void decomp7(const float* __restrict__ x, const float* __restrict__ M7,
                        float* __restrict__ SEAS7, float* __restrict__ TREND7)
{
    int idx = blockIdx.x * 256 + threadIdx.x;  // TG*7
    int c = idx % 7, bt = idx / 7, t = bt & 1023, b = bt >> 10;
    if (t < 512) {
        int s0 = t + 512;
        float s = 0.f;
        #pragma unroll
        for (int w = -12; w <= 12; ++w) {
            int tt = s0 + w; tt = tt < 0 ? 0 : (tt > 1023 ? 1023 : tt);
            s += x[(size_t)(b*1024+tt)*7 + c];
        }
        float m = s * (1.f/25.f);
        SEAS7[idx] = x[(size_t)(b*1024+s0)*7 + c] - m;
        TREND7[idx] = m;
    } else {
        SEAS7[idx] = 0.f;
        TREND7[idx] = M7[b*7 + c];
    }
}

__launch_bounds__(256)
__global__ void trendconv_acc(const float* __restrict__ T, const float* __restrict__ W,
                              float* __restrict__ TREND7)
{
    int idx = blockIdx.x * 256 + threadIdx.x;  // TG*7
    int co = idx % 7, bt = idx / 7, t = bt & 1023;
    int base = bt - t;
    float acc = 0.f;
    for (int j = 0; j < 3; ++j) {
        int tt = (t + 1023 + j) & 1023;
        const float* r = T + ((size_t)(base + tt) << 9);
        const float* wj = W + j*512*7 + co;
        for (int c = 0; c < 512; ++c) acc += r[c] * wj[c*7];
    }
    TREND7[idx] += acc;
}

__launch_bounds__(256)
__global__ void final_out(const float* __restrict__ X, const float* __restrict__ PW,
                          const float* __restrict__ PB, const float* __restrict__ TREND7,
                          float* __restrict__ out)
{
    int idx = blockIdx.x * 256 + threadIdx.x;  // G*512*7
    int c = idx % 7, btt = idx / 7, tt = btt & 511, b = btt >> 9;
    int t = tt + 512;
    float acc = PB[c] + TREND7[(size_t)(b*1024 + t)*7 + c];
    const float* xr = X + ((size_t)(b*1024 + t) << 9);
    for (int d = 0; d < 512; ++d) acc += xr[d] * PW[d*7 + c];
    out[idx] = acc;
}

__launch_bounds__(256)
__global__ void sentinel(float* __restrict__ out, int n)
{
    int i = blockIdx.x * 256 + threadIdx.x;
    if (i < n) out[i] = -54321.0f;
}

// ------------------------------------------------------------------
extern "C" void kernel_launch(void* const* d_in, const int* in_sizes, int n_in,
                              void* d_out, int out_size, void* d_ws, size_t ws_size,
                              hipStream_t stream)
{
    const float* x_enc      = (const float*)d_in[0];
    const float* x_mark_enc = (const float*)d_in[1];
    const float* x_mark_dec = (const float*)d_in[3];
    const float* W_enc_tok  = (const float*)d_in[4];
    const float* W_enc_tem  = (const float*)d_in[5];
    const float* W_dec_tok  = (const float*)d_in[6];
    const float* W_dec_tem  = (const float*)d_in[7];
    const float* enc_attn_W = (const float*)d_in[8];
    const float* enc_attn_b = (const float*)d_in[9];
    const float* enc_ff1    = (const float*)d_in[10];
    const float* enc_ff2    = (const float*)d_in[11];
    const float* enc_ln_w   = (const float*)d_in[12];
    const float* enc_ln_b   = (const float*)d_in[13];
    const float* dec_self_W = (const float*)d_in[14];
    const float* dec_self_b = (const float*)d_in[15];
    const float* dec_cross_W= (const float*)d_in[16];
    const float* dec_cross_b= (const float*)d_in[17];
    const float* dec_ff1    = (const float*)d_in[18];
    const float* dec_ff2    = (const float*)d_in[19];
    const float* dec_trend_W= (const float*)d_in[20];
    const float* dec_ln_w   = (const float*)d_in[21];
    const float* dec_ln_b   = (const float*)d_in[22];
    const float* proj_W     = (const float*)d_in[23];
    const float* proj_b     = (const float*)d_in[24];
    float* out = (float*)d_out;

    const size_t ATT_B = (size_t)16 * 2 * 262144 * 2;   // 16 attn mats hi+lo
    const size_t FF_B  = (size_t)3 * 2 * 1048576 * 2;   // 3 ffX mats hi+lo
    const size_t WBYTES = ATT_B + 2 * FF_B + 4096;

    auto need = [&](int g) -> size_t {
        size_t TGl = (size_t)g * 1024;
        size_t fp32acts = 4 * TGl * 512 * 4;       // XA,Qb,Kb,Vb
        size_t pairs    = 8 * TGl * 512 * 2;       // SA,SE,Q,K hi/lo
        size_t pb = (g < 8) ? g : 8;
        size_t scr  = pb * 1024 * 1024 * 4;
        size_t part = pb * 32 * 1024 * 4;
        size_t pc   = (size_t)g * 4096 * 4;
        size_t misc = (size_t)g * (7 + 2*7168 + 16) * 4 + 65536;
        return WBYTES + fp32acts + pairs + scr + part + pc + misc + 16384;
    };
    int G = 0;
    for (int g = 32; g >= 1; g >>= 1) if (need(g) <= ws_size) { G = g; break; }
    if (G == 0) {
        sentinel<<<(out_size + 255) / 256, 256, 0, stream>>>(out, out_size);
        return;
    }
    const int TG = G * 1024;
    const int PB = (G < 8) ? G : 8, NSUB = G / PB;
    const int MC = TG / 4;

    char* p = (char*)d_ws;
    auto carve = [&](size_t bytes) -> char* {
        char* r = p; p += (bytes + 255) & ~(size_t)255; return r;
    };
    ushortb* ATT = (ushortb*)carve(ATT_B);
    ushortb* FF1 = (ushortb*)carve(FF_B);
    ushortb* FF2 = (ushortb*)carve(FF_B);

    const size_t ACTB = (size_t)TG * 512 * 4;
    const size_t SPLB = (size_t)TG * 512 * 2;
    float* XA   = (float*)carve(ACTB);
    float* Qb   = (float*)carve(ACTB);
    float* Kb   = (float*)carve(ACTB);
    float* Vb   = (float*)carve(ACTB);
    ushortb* SAh = (ushortb*)carve(SPLB);
    ushortb* SAl = (ushortb*)carve(SPLB);
    ushortb* SEh = (ushortb*)carve(SPLB);
    ushortb* SEl = (ushortb*)carve(SPLB);
    ushortb* Qh  = (ushortb*)carve(SPLB);
    ushortb* Ql  = (ushortb*)carve(SPLB);
    ushortb* Kh  = (ushortb*)carve(SPLB);   // also FFN mid
    ushortb* Kl  = (ushortb*)carve(SPLB);
    float* SCR   = (float*)carve((size_t)PB * 1024 * 1024 * 4);
    float* PART  = (float*)carve((size_t)PB * 32 * 1024 * 4);
    float* PC    = (float*)carve((size_t)G * 4096 * 4);
    float* M7    = (float*)carve((size_t)G * 7 * 4);
    float* SEAS7 = (float*)carve((size_t)G * 1024 * 7 * 4);
    float* TREND7= (float*)carve((size_t)G * 1024 * 7 * 4);
    float* WGT   = (float*)carve((size_t)G * 6 * 4);
    int*   DELAY = (int*)  carve((size_t)G * 6 * 4);

    // ---- weight transform (once per launch) ----
    for (int m = 0; m < 8; ++m)
        wsplit_t<<<1024,256,0,stream>>>(enc_attn_W + (size_t)m*262144,
                                        ATT + (size_t)m*524288, ATT + (size_t)m*524288 + 262144, 512, 512);
    for (int j = 0; j < 4; ++j)
        wsplit_t<<<1024,256,0,stream>>>(dec_self_W + (size_t)j*262144,
                                        ATT + (size_t)(8+j)*524288, ATT + (size_t)(8+j)*524288 + 262144, 512, 512);
    for (int j = 0; j < 4; ++j)
        wsplit_t<<<1024,256,0,stream>>>(dec_cross_W + (size_t)j*262144,
                                        ATT + (size_t)(12+j)*524288, ATT + (size_t)(12+j)*524288 + 262144, 512, 512);
    for (int l = 0; l < 2; ++l) {
        wsplit_t<<<4096,256,0,stream>>>(enc_ff1 + (size_t)l*1048576,
                                        FF1 + (size_t)l*2097152, FF1 + (size_t)l*2097152 + 1048576, 512, 2048);
        wsplit_t<<<4096,256,0,stream>>>(enc_ff2 + (size_t)l*1048576,
                                        FF2 + (size_t)l*2097152, FF2 + (size_t)l*2097152 + 1048576, 2048, 512);
    }
    wsplit_t<<<4096,256,0,stream>>>(dec_ff1, FF1 + (size_t)2*2097152, FF1 + (size_t)2*2097152 + 1048576, 512, 2048);
    wsplit_t<<<4096,256,0,stream>>>(dec_ff2, FF2 + (size_t)2*2097152, FF2 + (size_t)2*2097152 + 1048576, 2048, 512);

    for (int g0 = 0; g0 < 32; g0 += G) {
        const float* xe  = x_enc      + (size_t)g0 * 1024 * 7;
        const float* me  = x_mark_enc + (size_t)g0 * 1024 * 4;
        const float* md  = x_mark_dec + (size_t)g0 * 1024 * 4;
        float*       outg= out        + (size_t)g0 * 512 * 7;

        // Xq: fp32 residual stream; (aqh,aql): its split; (kvh,kvl): KV split
        auto attn = [&](const float* Xq, const ushortb* aqh, const ushortb* aql,
                        const ushortb* kvh, const ushortb* kvl,
                        int mb, const float* bv, float* dest) {
            const ushortb* W0h = ATT + (size_t)(mb+0)*524288, *W0l = W0h + 262144;
            const ushortb* W1h = ATT + (size_t)(mb+1)*524288, *W1l = W1h + 262144;
            const ushortb* W2h = ATT + (size_t)(mb+2)*524288, *W2l = W2h + 262144;
            const ushortb* W3h = ATT + (size_t)(mb+3)*524288, *W3l = W3h + 262144;
            dim3 gp(4, TG/128);
            gemm_sp<<<gp,256,0,stream>>>(aqh,aql,0, W0h,W0l,0, bv+0,    nullptr, nullptr,0, Qh,Ql, TG,512,512,0);
            gemm_sp<<<gp,256,0,stream>>>(kvh,kvl,0, W1h,W1l,0, bv+512,  nullptr, nullptr,0, Kh,Kl, TG,512,512,0);
            gemm_sp<<<gp,256,0,stream>>>(kvh,kvl,0, W2h,W2l,0, bv+1024, nullptr, Vb,0, nullptr,nullptr, TG,512,512,0);
            for (int s = 0; s < NSUB; ++s) {
                size_t so = (size_t)s * PB * 524288;
                gemm_sp<<<dim3(8,8,PB),256,0,stream>>>(Qh+so,Ql+so,524288, Kh+so,Kl+so,524288,
                                                       nullptr, nullptr, SCR,1048576, nullptr,nullptr,
                                                       1024,1024,512,0);
                corr_diag<<<dim3(32,PB),256,0,stream>>>(SCR, PART);
                topk6p<<<PB,256,0,stream>>>(PART, DELAY + s*PB*6, WGT + s*PB*6);
            }
            gather6s<<<TG/2,256,0,stream>>>(Vb, DELAY, WGT, Qh, Ql);
            gemm_sp<<<gp,256,0,stream>>>(Qh,Ql,0, W3h,W3l,0, bv+1536, Xq, dest,0, nullptr,nullptr, TG,512,512,0);
        };
        auto ffn = [&](const float* Xin, const ushortb* xh, const ushortb* xl,
                       int f1i, int f2i, float* dest) {
            const ushortb* F1h = FF1 + (size_t)f1i*2097152, *F1l = F1h + 1048576;
            const ushortb* F2h = FF2 + (size_t)f2i*2097152, *F2l = F2h + 1048576;
            for (int c = 0; c < 4; ++c) {
                size_t ro = (size_t)c * MC * 512;
                gemm_sp<<<dim3(16, MC/128),256,0,stream>>>(xh+ro,xl+ro,0, F1h,F1l,0,
                                                           nullptr, nullptr, nullptr,0, Kh,Kl,
                                                           MC,2048,512,1);
                gemm_sp<<<dim3(4, MC/128),256,0,stream>>>(Kh,Kl,0, F2h,F2l,0,
                                                          nullptr, Xin+ro, dest+ro,0, nullptr,nullptr,
                                                          MC,512,2048,0);
            }
        };

        // ---------------- encoder ----------------
        embed_es<<<TG*2,256,0,stream>>>(xe, me, W_enc_tok, W_enc_tem, XA, SAh, SAl);
        for (int l = 0; l < 2; ++l) {
            attn(XA, SAh, SAl, SAh, SAl, l*4, enc_attn_b + (size_t)l*4*512, Kb);
            decomp512s<<<TG*2,256,0,stream>>>(Kb, XA, SAh, SAl, nullptr);
            ffn(XA, SAh, SAl, l, l, Kb);
            decomp512s<<<TG*2,256,0,stream>>>(Kb, XA, SAh, SAl, nullptr);
        }
        ln_rows<<<TG,256,0,stream>>>(XA, enc_ln_w, enc_ln_b, Kb);
        colmean_p<<<G*16,256,0,stream>>>(Kb, PC);
        submean_s<<<TG*2,256,0,stream>>>(Kb, PC, nullptr, SEh, SEl);

        // ---------------- decoder prep ----------------
        mean7<<<G*7,256,0,stream>>>(xe, M7);
        decomp7<<<G*28,256,0,stream>>>(xe, M7, SEAS7, TREND7);
        embed_es<<<TG*2,256,0,stream>>>(SEAS7, md, W_dec_tok, W_dec_tem, XA, SAh, SAl);

        // ---------------- decoder layer ----------------
        attn(XA, SAh, SAl, SAh, SAl, 8, dec_self_b, Kb);
        decomp512s<<<TG*2,256,0,stream>>>(Kb, XA, SAh, SAl, Qb);
        trendconv_acc<<<G*28,256,0,stream>>>(Qb, dec_trend_W, TREND7);

        attn(XA, SAh, SAl, SEh, SEl, 12, dec_cross_b, Kb);
        decomp512s<<<TG*2,256,0,stream>>>(Kb, XA, SAh, SAl, Qb);
        trendconv_acc<<<G*28,256,0,stream>>>(Qb, dec_trend_W, TREND7);

        ffn(XA, SAh, SAl, 2, 2, Kb);
        decomp512s<<<TG*2,256,0,stream>>>(Kb, XA, SAh, SAl, Qb);
        trendconv_acc<<<G*28,256,0,stream>>>(Qb, dec_trend_W, TREND7);

        ln_rows<<<TG,256,0,stream>>>(XA, dec_ln_w, dec_ln_b, Kb);
        colmean_p<<<G*16,256,0,stream>>>(Kb, PC);
        submean_s<<<TG*2,256,0,stream>>>(Kb, PC, Qb, nullptr, nullptr);

        final_out<<<G*14,256,0,stream>>>(Qb, proj_W, proj_b, TREND7, outg);
    }
}

// Round 6
// 8590.491 us; speedup vs baseline: 1.8000x; 1.4154x over previous
//
#include <hip/hip_runtime.h>

typedef unsigned short ushortb;
typedef __attribute__((ext_vector_type(8))) short bf16x8;
typedef __attribute__((ext_vector_type(4))) float f32x4;

__device__ __forceinline__ float b2f(ushortb u) {
    union { unsigned int i; float f; } c; c.i = ((unsigned int)u) << 16; return c.f;
}
__device__ __forceinline__ ushortb f2b(float f) {
    union { float f; unsigned int i; } c; c.f = f;
    unsigned int r = c.i + 0x7FFFu + ((c.i >> 16) & 1u);
    return (ushortb)(r >> 16);
}
__device__ __forceinline__ float gelu_f(float x) {
    return 0.5f * x * (1.0f + erff(x * 0.7071067811865475f));
}

// async global->LDS, 16B per lane; LDS dest = wave-uniform base + lane*16
__device__ __forceinline__ void ld16(const void* g, void* l) {
    __builtin_amdgcn_global_load_lds(
        (const __attribute__((address_space(1))) unsigned int*)g,
        (__attribute__((address_space(3))) unsigned int*)l, 16, 0, 0);
}

// ------------------------------------------------------------------
// Split-bf16 MFMA GEMM (NT): C = act(resid + A@B^T + bias)
// A: Ah/Al rows [M], lda; B: Bh/Bl rows [gridDim.x*128], ldb. 3-term
// AhBh+AlBh+AhBl (fp32 fidelity). 128x128 tile, BK=32, 256 thr.
// z-batched via sA/sB/sC element strides. M%128==0, K%32==0.
// ------------------------------------------------------------------
__launch_bounds__(256)
__global__ void gemm_sp(const ushortb* __restrict__ Ah, const ushortb* __restrict__ Al,
                        int lda, long sA,
                        const ushortb* __restrict__ Bh, const ushortb* __restrict__ Bl,
                        int ldb, long sB,
                        const float* __restrict__ bias, const float* __restrict__ resid,
                        float* __restrict__ Cf, ushortb* __restrict__ Ch, ushortb* __restrict__ Cl,
                        int ldc, long sC, int K, int act)
{
    __shared__ __align__(16) ushortb LDS[16384];   // 4 planes x [128][32]
    const int tid = threadIdx.x;
    const int wv = tid >> 6, ln = tid & 63;
    const int fr = ln & 15, fq = ln >> 4;
    const int m0 = blockIdx.y << 7, n0 = blockIdx.x << 7;
    const int wr = (wv & 1) << 6, wc = (wv >> 1) << 6;
    const size_t zb = blockIdx.z;

    const ushortb* gb; int ld;
    if (wv == 0)      { gb = Ah + zb * (size_t)sA; ld = lda; }
    else if (wv == 1) { gb = Al + zb * (size_t)sA; ld = lda; }
    else if (wv == 2) { gb = Bh + zb * (size_t)sB; ld = ldb; }
    else              { gb = Bl + zb * (size_t)sB; ld = ldb; }
    const int rbase = (wv < 2) ? m0 : n0;
    const ushortb* gp = gb + (size_t)(rbase + (ln >> 2)) * ld + (ln & 3) * 8;
    ushortb* lplane = LDS + wv * 4096;
    const size_t rstep = (size_t)ld << 4;   // 16 rows

    f32x4 acc[4][4] = {};

    for (int k0 = 0; k0 < K; k0 += 32) {
        __syncthreads();
        #pragma unroll
        for (int i = 0; i < 8; ++i)
            ld16(gp + (size_t)i * rstep, lplane + i * 512);
        gp += 32;
        __syncthreads();
        bf16x8 afh[4], afl[4], bfh[4], bfl[4];
        #pragma unroll
        for (int t = 0; t < 4; ++t) {
            int ra = ((wr + t*16 + fr) << 5) + (fq << 3);
            int rb = ((wc + t*16 + fr) << 5) + (fq << 3);
            afh[t] = *(const bf16x8*)(const void*)(LDS + ra);
            afl[t] = *(const bf16x8*)(const void*)(LDS + 4096 + ra);
            bfh[t] = *(const bf16x8*)(const void*)(LDS + 8192 + rb);
            bfl[t] = *(const bf16x8*)(const void*)(LDS + 12288 + rb);
        }
        #pragma unroll
        for (int tm = 0; tm < 4; ++tm)
            #pragma unroll
            for (int tn = 0; tn < 4; ++tn) {
                f32x4 c = acc[tm][tn];
                c = __builtin_amdgcn_mfma_f32_16x16x32_bf16(afh[tm], bfh[tn], c, 0, 0, 0);
                c = __builtin_amdgcn_mfma_f32_16x16x32_bf16(afl[tm], bfh[tn], c, 0, 0, 0);
                c = __builtin_amdgcn_mfma_f32_16x16x32_bf16(afh[tm], bfl[tn], c, 0, 0, 0);
                acc[tm][tn] = c;
            }
    }

    if (Cf)    Cf += zb * (size_t)sC;
    if (resid) resid += zb * (size_t)sC;
    if (Ch) { Ch += zb * (size_t)sC; Cl += zb * (size_t)sC; }
    #pragma unroll
    for (int tm = 0; tm < 4; ++tm) {
        #pragma unroll
        for (int tn = 0; tn < 4; ++tn) {
            int row0 = m0 + wr + tm*16 + fq*4;
            int col  = n0 + wc + tn*16 + fr;
            #pragma unroll
            for (int r = 0; r < 4; ++r) {
                float v = acc[tm][tn][r];
                size_t off = (size_t)(row0 + r) * ldc + col;
                if (bias)  v += bias[col];
                if (resid) v += resid[off];
                if (act)   v = gelu_f(v);
                if (Cf) Cf[off] = v;
                if (Ch) { ushortb h = f2b(v); Ch[off] = h; Cl[off] = f2b(v - b2f(h)); }
            }
        }
    }
}

// ------------------------------------------------------------------
// Coalesced transpose+split of attn weights into pooled layout.
// src mat m: [512,512] row-major. Pool block a (2097152 elems):
//   QKVh @0 (1536x512), QKVl @786432, Oh @1572864, Ol @1835008.
// which: 0=enc (a=m>>2, j=m&3), 1=dec_self (a=2,j=m), 2=dec_cross (a=3,j=m)
// ------------------------------------------------------------------
__launch_bounds__(256)
__global__ void wsplit_att(const float* __restrict__ W, ushortb* __restrict__ pool, int which)
{
    __shared__ float t[32][33];
    const int m = blockIdx.z;
    const int kb = blockIdx.y << 5, nb = blockIdx.x << 5;
    const int c = threadIdx.x & 31, rr = threadIdx.x >> 5;
    const float* Wm = W + (size_t)m * 262144;
    #pragma unroll
    for (int i = 0; i < 4; ++i)
        t[rr + i*8][c] = Wm[(size_t)(kb + rr + i*8) * 512 + nb + c];
    __syncthreads();
    const int a = (which == 0) ? (m >> 2) : (which + 1);
    const int j = (which == 0) ? (m & 3) : m;
    const size_t hi = (size_t)a * 2097152 + (j < 3 ? (size_t)j * 262144 : 1572864);
    const size_t lo = hi + (j < 3 ? 786432 : 262144);
    #pragma unroll
    for (int i = 0; i < 4; ++i) {
        int n = nb + rr + i*8, k = kb + c;
        float v = t[c][rr + i*8];
        ushortb h = f2b(v);
        pool[hi + (size_t)n * 512 + k] = h;
        pool[lo + (size_t)n * 512 + k] = f2b(v - b2f(h));
    }
}

// generic FF transpose+split: src [K,N] -> dest mat m hi @ m*2097152, lo +1048576
__launch_bounds__(256)
__global__ void wsplit_ff(const float* __restrict__ W, ushortb* __restrict__ dh,
                          int K, int N)
{
    __shared__ float t[32][33];
    const int m = blockIdx.z;
    const int kb = blockIdx.y << 5, nb = blockIdx.x << 5;
    const int c = threadIdx.x & 31, rr = threadIdx.x >> 5;
    const float* Wm = W + (size_t)m * K * N;
    #pragma unroll
    for (int i = 0; i < 4; ++i)
        t[rr + i*8][c] = Wm[(size_t)(kb + rr + i*8) * N + nb + c];
    __syncthreads();
    ushortb* Dh = dh + (size_t)m * 2097152;
    ushortb* Dl = Dh + 1048576;
    #pragma unroll
    for (int i = 0; i < 4; ++i) {
        int n = nb + rr + i*8, k = kb + c;
        float v = t[c][rr + i*8];
        ushortb h = f2b(v);
        Dh[(size_t)n * K + k] = h;
        Dl[(size_t)n * K + k] = f2b(v - b2f(h));
    }
}

// Diagonal sums: PART[pb][chunk][tau] = sum_{s in chunk} P[pb][s][(s-tau)&1023]
__launch_bounds__(256)
__global__ void corr_diag(const float* __restrict__ P, float* __restrict__ PART)
{
    __shared__ float lc[1024];
    const int pb = blockIdx.y, chunk = blockIdx.x, tid = threadIdx.x;
    #pragma unroll
    for (int k = 0; k < 4; ++k) lc[tid + (k<<8)] = 0.f;
    __syncthreads();
    const float* Pb = P + ((size_t)pb << 20);
    for (int s = chunk << 5; s < (chunk << 5) + 32; ++s) {
        const float* row = Pb + (s << 10);
        #pragma unroll
        for (int k = 0; k < 4; ++k) {
            int t = tid + (k << 8);
            lc[(s - t) & 1023] += row[t];
        }
        __syncthreads();
    }
    float* dst = PART + ((size_t)pb << 15) + (chunk << 10);
    #pragma unroll
    for (int k = 0; k < 4; ++k) { int tau = tid + (k<<8); dst[tau] = lc[tau]; }
}

// top-6 + softmax per local batch; reduces PART chunks inline
__launch_bounds__(256)
__global__ void topk6p(const float* __restrict__ PART, int* __restrict__ DELAY,
                       float* __restrict__ WGT)
{
    __shared__ float v[1024];
    __shared__ float rv[256];
    __shared__ int   ri[256];
    __shared__ float wv6[6];
    __shared__ int   wi6[6];
    const int b = blockIdx.x, tid = threadIdx.x;
    #pragma unroll
    for (int k = 0; k < 4; ++k) {
        int tau = tid + (k << 8);
        const float* pp = PART + ((size_t)b << 15) + tau;
        float s = 0.f;
        #pragma unroll
        for (int ch = 0; ch < 32; ++ch) s += pp[ch << 10];
        v[tau] = s * (1.f / 512.f);
    }
    __syncthreads();
    for (int it = 0; it < 6; ++it) {
        float best = v[tid]; int bi = tid;
        #pragma unroll
        for (int k = 1; k < 4; ++k) {
            int i = tid + (k << 8);
            float xv = v[i];
            if (xv > best) { best = xv; bi = i; }
        }
        rv[tid] = best; ri[tid] = bi;
        __syncthreads();
        for (int s = 128; s > 0; s >>= 1) {
            if (tid < s) {
                if (rv[tid+s] > rv[tid] || (rv[tid+s] == rv[tid] && ri[tid+s] < ri[tid])) {
                    rv[tid] = rv[tid+s]; ri[tid] = ri[tid+s];
                }
            }
            __syncthreads();
        }
        if (tid == 0) { wv6[it] = rv[0]; wi6[it] = ri[0]; v[ri[0]] = -1e30f; }
        __syncthreads();
    }
    if (tid == 0) {
        float mx = wv6[0], s = 0.f, e[6];
        #pragma unroll
        for (int i = 0; i < 6; ++i) { e[i] = expf(wv6[i] - mx); s += e[i]; }
        #pragma unroll
        for (int i = 0; i < 6; ++i) { WGT[b*6+i] = e[i]/s; DELAY[b*6+i] = wi6[i]; }
    }
}

// gather from merged QKV planes (V = cols 1024..1535, row stride 1536)
__launch_bounds__(256)
__global__ void gather6m(const ushortb* __restrict__ Vh, const ushortb* __restrict__ Vl,
                         const int* __restrict__ DELAY, const float* __restrict__ WGT,
                         ushortb* __restrict__ Gh, ushortb* __restrict__ Gl)
{
    int idx = blockIdx.x * 256 + threadIdx.x;     // TG*128 threads
    int d0 = (idx & 127) << 2, bt = idx >> 7, t = bt & 1023, b = bt >> 10;
    const size_t bo = (size_t)b * 1024 * 1536;
    float a0=0,a1=0,a2=0,a3=0;
    #pragma unroll
    for (int i = 0; i < 6; ++i) {
        int s = (t + DELAY[b*6+i]) & 1023;
        float w = WGT[b*6+i];
        size_t ro = bo + (size_t)s * 1536 + d0;
        uint2 hv = *(const uint2*)(Vh + ro);
        uint2 lv = *(const uint2*)(Vl + ro);
        a0 += w * (b2f((ushortb)(hv.x & 0xFFFFu)) + b2f((ushortb)(lv.x & 0xFFFFu)));
        a1 += w * (b2f((ushortb)(hv.x >> 16))     + b2f((ushortb)(lv.x >> 16)));
        a2 += w * (b2f((ushortb)(hv.y & 0xFFFFu)) + b2f((ushortb)(lv.y & 0xFFFFu)));
        a3 += w * (b2f((ushortb)(hv.y >> 16))     + b2f((ushortb)(lv.y >> 16)));
    }
    ushortb h0=f2b(a0), h1=f2b(a1), h2=f2b(a2), h3=f2b(a3);
    ushortb e0=f2b(a0-b2f(h0)), e1=f2b(a1-b2f(h1)), e2=f2b(a2-b2f(h2)), e3=f2b(a3-b2f(h3));
    uint2 hp, lp;
    hp.x = (unsigned)h0 | ((unsigned)h1<<16); hp.y = (unsigned)h2 | ((unsigned)h3<<16);
    lp.x = (unsigned)e0 | ((unsigned)e1<<16); lp.y = (unsigned)e2 | ((unsigned)e3<<16);
    size_t oo = ((size_t)bt << 9) + d0;
    *(uint2*)(Gh + oo) = hp; *(uint2*)(Gl + oo) = lp;
}

// series_decomp + fused split: S=X-movmean25 (fp32 + hi/lo), T=movmean optional
__launch_bounds__(256)
__global__ void decomp512s(const float* __restrict__ X, float* __restrict__ S,
                           ushortb* __restrict__ Sh, ushortb* __restrict__ Sl,
                           float* __restrict__ T)
{
    int idx = blockIdx.x * 256 + threadIdx.x;     // TG*512
    int d = idx & 511, bt = idx >> 9, t = bt & 1023;
    int base = bt - t;
    const float* Xb = X + ((size_t)base << 9) + d;
    float s = 0.f;
    #pragma unroll
    for (int w = -12; w <= 12; ++w) {
        int tt = t + w; tt = tt < 0 ? 0 : (tt > 1023 ? 1023 : tt);
        s += Xb[tt << 9];
    }
    float m = s * (1.f / 25.f);
    float v = X[idx] - m;
    S[idx] = v;
    ushortb h = f2b(v);
    Sh[idx] = h; Sl[idx] = f2b(v - b2f(h));
    if (T) T[idx] = m;
}

__launch_bounds__(256)
__global__ void ln_rows(const float* __restrict__ X, const float* __restrict__ w,
                        const float* __restrict__ bias, float* __restrict__ Y)
{
    __shared__ float r1[256], r2[256];
    const int row = blockIdx.x, tid = threadIdx.x;
    const float* xr = X + (size_t)row * 512;
    float x0 = xr[tid], x1 = xr[tid + 256];
    r1[tid] = x0 + x1; r2[tid] = x0*x0 + x1*x1;
    __syncthreads();
    for (int s = 128; s > 0; s >>= 1) {
        if (tid < s) { r1[tid] += r1[tid+s]; r2[tid] += r2[tid+s]; }
        __syncthreads();
    }
    float mu = r1[0] * (1.f/512.f);
    float var = r2[0] * (1.f/512.f) - mu*mu;
    float rstd = rsqrtf(var + 1e-5f);
    float* yr = Y + (size_t)row * 512;
    yr[tid]       = (x0 - mu) * rstd * w[tid]     + bias[tid];
    yr[tid + 256] = (x1 - mu) * rstd * w[tid+256] + bias[tid+256];
}

// column-mean partials: PC[b][d][c] = (1/1024) * sum_{t in chunk c} Y[b,t,d]
__launch_bounds__(256)
__global__ void colmean_p(const float* __restrict__ Y, float* __restrict__ PC)
{
    int i = blockIdx.x * 256 + threadIdx.x;   // G*4096
    int b = i >> 12, r = i & 4095, d = r >> 3, c = r & 7;
    const float* p = Y + ((size_t)b << 19) + ((size_t)(c << 7) << 9) + d;
    float s = 0.f;
    for (int t = 0; t < 128; ++t) s += p[t << 9];
    PC[i] = s * (1.f/1024.f);
}

// Z = Y - colmean (fp32 out and/or split out)
__launch_bounds__(256)
__global__ void submean_s(const float* __restrict__ Y, const float* __restrict__ PC,
                          float* __restrict__ Zf, ushortb* __restrict__ Zh,
                          ushortb* __restrict__ Zl)
{
    int idx = blockIdx.x * 256 + threadIdx.x;
    int d = idx & 511, b = idx >> 19;
    const float* pc = PC + ((size_t)b << 12) + (d << 3);
    float m = ((pc[0]+pc[1])+(pc[2]+pc[3]))+((pc[4]+pc[5])+(pc[6]+pc[7]));
    float v = Y[idx] - m;
    if (Zf) Zf[idx] = v;
    if (Zh) { ushortb h = f2b(v); Zh[idx] = h; Zl[idx] = f2b(v - b2f(h)); }
}

// embedding: circ conv3 (C=7) + mark @ Wtem, fused split
__launch_bounds__(256)
__global__ void embed_es(const float* __restrict__ x, const float* __restrict__ mark,
                         const float* __restrict__ Wtok, const float* __restrict__ Wtem,
                         float* __restrict__ out, ushortb* __restrict__ Oh,
                         ushortb* __restrict__ Ol)
{
    int idx = blockIdx.x * 256 + threadIdx.x;
    int d = idx & 511, bt = idx >> 9, t = bt & 1023, b = bt >> 10;
    float acc = 0.f;
    #pragma unroll
    for (int j = 0; j < 3; ++j) {
        int tt = (t + 1023 + j) & 1023;
        const float* xr = x + (size_t)(b*1024 + tt)*7;
        #pragma unroll
        for (int c = 0; c < 7; ++c)
            acc += xr[c] * Wtok[(j*7+c)*512 + d];
    }
    const float* mr = mark + (size_t)bt*4;
    #pragma unroll
    for (int m = 0; m < 4; ++m) acc += mr[m] * Wtem[m*512 + d];
    out[idx] = acc;
    ushortb h = f2b(acc);
    Oh[idx] = h; Ol[idx] = f2b(acc - b2f(h));
}

__launch_bounds__(256)
__global__ void mean7(const float* __restrict__ x, float* __restrict__ M7)
{
    __shared__ float r[256];
    int bc = blockIdx.x, b = bc / 7, c = bc % 7, tid = threadIdx.x;
    float s = 0.f;
    for (int t = tid; t < 1024; t += 256) s += x[(size_t)(b*1024+t)*7 + c];
    r[tid] = s; __syncthreads();
    for (int st = 128; st > 0; st >>= 1) { if (tid < st) r[tid] += r[tid+st]; __syncthreads(); }
    if (tid == 0) M7[bc] = r[0] * (1.f/1024.f);
}

__launch_bounds__(256)
__global__ void decomp7(const float* __restrict__ x, const float* __restrict__ M7,
                        float* __restrict__ SEAS7, float* __restrict__ TREND7)
{
    int idx = blockIdx.x * 256 + threadIdx.x;  // TG*7
    int c = idx % 7, bt = idx / 7, t = bt & 1023, b = bt >> 10;
    if (t < 512) {
        int s0 = t + 512;
        float s = 0.f;
        #pragma unroll
        for (int w = -12; w <= 12; ++w) {
            int tt = s0 + w; tt = tt < 0 ? 0 : (tt > 1023 ? 1023 : tt);
            s += x[(size_t)(b*1024+tt)*7 + c];
        }
        float m = s * (1.f/25.f);
        SEAS7[idx] = x[(size_t)(b*1024+s0)*7 + c] - m;
        TREND7[idx] = m;
    } else {
        SEAS7[idx] = 0.f;
        TREND7[idx] = M7[b*7 + c];
    }
}

__launch_bounds__(256)
__global__ void trendconv_acc(const float* __restrict__ T, const float* __restrict__ W,
                              float* __restrict__ TREND7)
{
    int idx = blockIdx.x * 256 + threadIdx.x;  // TG*7
    int co = idx % 7, bt = idx / 7, t = bt & 1023;
    int base = bt - t;
    float acc = 0.f;
    for (int j = 0; j < 3; ++j) {
        int tt = (t + 1023 + j) & 1023;
        const float* r = T + ((size_t)(base + tt) << 9);
        const float* wj = W + j*512*7 + co;
        for (int c = 0; c < 512; ++c) acc += r[c] * wj[c*7];
    }
    TREND7[idx] += acc;
}

__launch_bounds__(256)
__global__ void final_out(const float* __restrict__ X, const float* __restrict__ PW,
                          const float* __restrict__ PB, const float* __restrict__ TREND7,
                          float* __restrict__ out)
{
    int idx = blockIdx.x * 256 + threadIdx.x;  // G*512*7
    int c = idx % 7, btt = idx / 7, tt = btt & 511, b = btt >> 9;
    int t = tt + 512;
    float acc = PB[c] + TREND7[(size_t)(b*1024 + t)*7 + c];
    const float* xr = X + ((size_t)(b*1024 + t) << 9);
    for (int d = 0; d < 512; ++d) acc += xr[d] * PW[d*7 + c];
    out[idx] = acc;
}

__launch_bounds__(256)
__global__ void sentinel(float* __restrict__ out, int n)
{
    int i = blockIdx.x * 256 + threadIdx.x;
    if (i < n) out[i] = -54321.0f;
}

// ------------------------------------------------------------------
extern "C" void kernel_launch(void* const* d_in, const int* in_sizes, int n_in,
                              void* d_out, int out_size, void* d_ws, size_t ws_size,
                              hipStream_t stream)
{
    const float* x_enc      = (const float*)d_in[0];
    const float* x_mark_enc = (const float*)d_in[1];
    const float* x_mark_dec = (const float*)d_in[3];
    const float* W_enc_tok  = (const float*)d_in[4];
    const float* W_enc_tem  = (const float*)d_in[5];
    const float* W_dec_tok  = (const float*)d_in[6];
    const float* W_dec_tem  = (const float*)d_in[7];
    const float* enc_attn_W = (const float*)d_in[8];
    const float* enc_attn_b = (const float*)d_in[9];
    const float* enc_ff1    = (const float*)d_in[10];
    const float* enc_ff2    = (const float*)d_in[11];
    const float* enc_ln_w   = (const float*)d_in[12];
    const float* enc_ln_b   = (const float*)d_in[13];
    const float* dec_self_W = (const float*)d_in[14];
    const float* dec_self_b = (const float*)d_in[15];
    const float* dec_cross_W= (const float*)d_in[16];
    const float* dec_cross_b= (const float*)d_in[17];
    const float* dec_ff1    = (const float*)d_in[18];
    const float* dec_ff2    = (const float*)d_in[19];
    const float* dec_trend_W= (const float*)d_in[20];
    const float* dec_ln_w   = (const float*)d_in[21];
    const float* dec_ln_b   = (const float*)d_in[22];
    const float* proj_W     = (const float*)d_in[23];
    const float* proj_b     = (const float*)d_in[24];
    float* out = (float*)d_out;

    // weight pools
    const size_t ATT_E = (size_t)4 * 2097152;   // 4 attn blocks
    const size_t FF_E  = (size_t)3 * 2097152;   // 3 mats each
    const size_t WBYTES = (ATT_E + 2 * FF_E) * 2 + 4096;

    auto need = [&](long g) -> size_t {
        size_t TGl = (size_t)g * 1024;
        size_t acts = 3 * TGl * 512 * 4;          // XA, TMP, TT
        size_t pairs = 2 * TGl * 512 * 2 * 2;     // SA, SE
        size_t r1 = TGl * 1536 * 2 * 2;           // QKV pair (>= MID)
        size_t r2 = (size_t)g * 1024 * 1024 * 4;  // SCR (>= SG pair)
        size_t part = (size_t)g * 32 * 1024 * 4;
        size_t misc = (size_t)g * (4096 + 7 + 2*7168 + 16) * 4 + 65536;
        return WBYTES + acts + pairs + r1 + r2 + part + misc + 16384;
    };
    int G = 0;
    for (int g = 32; g >= 1; g >>= 1) if (need(g) <= ws_size) { G = g; break; }
    if (G == 0) {
        sentinel<<<(out_size + 255) / 256, 256, 0, stream>>>(out, out_size);
        return;
    }
    const int TG = G * 1024;
    const int MCr = TG / 2;     // FFN row chunk (2 chunks)

    char* p = (char*)d_ws;
    auto carve = [&](size_t bytes) -> char* {
        char* r = p; p += (bytes + 255) & ~(size_t)255; return r;
    };
    ushortb* ATT = (ushortb*)carve(ATT_E * 2);
    ushortb* FF1 = (ushortb*)carve(FF_E * 2);
    ushortb* FF2 = (ushortb*)carve(FF_E * 2);

    const size_t ACTB = (size_t)TG * 512 * 4;
    const size_t SPLB = (size_t)TG * 512 * 2;
    float* XA  = (float*)carve(ACTB);
    float* TMP = (float*)carve(ACTB);
    float* TT  = (float*)carve(ACTB);
    ushortb* SAh = (ushortb*)carve(SPLB);
    ushortb* SAl = (ushortb*)carve(SPLB);
    ushortb* SEh = (ushortb*)carve(SPLB);
    ushortb* SEl = (ushortb*)carve(SPLB);
    char* R1 = carve((size_t)TG * 1536 * 2 * 2);     // QKV pair / MID pair
    char* R2 = carve((size_t)G * 1024 * 1024 * 4);   // SCR / SG pair
    float* PART  = (float*)carve((size_t)G * 32 * 1024 * 4);
    float* PC    = (float*)carve((size_t)G * 4096 * 4);
    float* M7    = (float*)carve((size_t)G * 7 * 4);
    float* SEAS7 = (float*)carve((size_t)G * 1024 * 7 * 4);
    float* TREND7= (float*)carve((size_t)G * 1024 * 7 * 4);
    float* WGT   = (float*)carve((size_t)G * 6 * 4);
    int*   DELAY = (int*)  carve((size_t)G * 6 * 4);

    ushortb* QKVh = (ushortb*)R1;
    ushortb* QKVl = QKVh + (size_t)TG * 1536;
    ushortb* MIDh = (ushortb*)R1;
    ushortb* MIDl = MIDh + (size_t)MCr * 2048;
    float*   SCR  = (float*)R2;
    ushortb* SGh  = (ushortb*)R2;
    ushortb* SGl  = SGh + (size_t)TG * 512;

    // ---- weight transform: 7 coalesced tiled launches ----
    wsplit_att<<<dim3(16,16,8),256,0,stream>>>(enc_attn_W, ATT, 0);
    wsplit_att<<<dim3(16,16,4),256,0,stream>>>(dec_self_W, ATT, 1);
    wsplit_att<<<dim3(16,16,4),256,0,stream>>>(dec_cross_W, ATT, 2);
    wsplit_ff<<<dim3(64,16,2),256,0,stream>>>(enc_ff1, FF1, 512, 2048);
    wsplit_ff<<<dim3(64,16,1),256,0,stream>>>(dec_ff1, FF1 + (size_t)2*2097152, 512, 2048);
    wsplit_ff<<<dim3(16,64,2),256,0,stream>>>(enc_ff2, FF2, 2048, 512);
    wsplit_ff<<<dim3(16,64,1),256,0,stream>>>(dec_ff2, FF2 + (size_t)2*2097152, 2048, 512);

    for (int g0 = 0; g0 < 32; g0 += G) {
        const float* xe  = x_enc      + (size_t)g0 * 1024 * 7;
        const float* me  = x_mark_enc + (size_t)g0 * 1024 * 4;
        const float* md  = x_mark_dec + (size_t)g0 * 1024 * 4;
        float*       outg= out        + (size_t)g0 * 512 * 7;

        // attn: Xq fp32 resid; (aqh,aql) Q-source split; (kvh,kvl) KV-source split
        auto attn = [&](const float* Xq, const ushortb* aqh, const ushortb* aql,
                        const ushortb* kvh, const ushortb* kvl, bool selfsame,
                        int a, const float* bv, float* dest) {
            const ushortb* Wqkvh = ATT + (size_t)a * 2097152;
            const ushortb* Wqkvl = Wqkvh + 786432;
            const ushortb* Woh   = Wqkvh + 1572864;
            const ushortb* Wol   = Wqkvh + 1835008;
            if (selfsame) {
                gemm_sp<<<dim3(12, TG/128),256,0,stream>>>(
                    aqh,aql,512,0, Wqkvh,Wqkvl,512,0, bv, nullptr,
                    nullptr, QKVh, QKVl, 1536,0, 512, 0);
            } else {
                gemm_sp<<<dim3(4, TG/128),256,0,stream>>>(
                    aqh,aql,512,0, Wqkvh,Wqkvl,512,0, bv, nullptr,
                    nullptr, QKVh, QKVl, 1536,0, 512, 0);
                gemm_sp<<<dim3(8, TG/128),256,0,stream>>>(
                    kvh,kvl,512,0, Wqkvh+262144,Wqkvl+262144,512,0, bv+512, nullptr,
                    nullptr, QKVh+512, QKVl+512, 1536,0, 512, 0);
            }
            // QK^T: A = Q cols, B = K cols (both in merged planes)
            gemm_sp<<<dim3(8,8,G),256,0,stream>>>(
                QKVh,QKVl,1536,(long)1024*1536, QKVh+512,QKVl+512,1536,(long)1024*1536,
                nullptr, nullptr, SCR, nullptr,nullptr, 1024,(long)1048576, 512, 0);
            corr_diag<<<dim3(32,G),256,0,stream>>>(SCR, PART);
            topk6p<<<G,256,0,stream>>>(PART, DELAY, WGT);
            gather6m<<<TG/2,256,0,stream>>>(QKVh+1024, QKVl+1024, DELAY, WGT, SGh, SGl);
            gemm_sp<<<dim3(4, TG/128),256,0,stream>>>(
                SGh,SGl,512,0, Woh,Wol,512,0, bv+1536, Xq,
                dest, nullptr,nullptr, 512,0, 512, 0);
        };
        auto ffn = [&](const float* Xin, const ushortb* xh, const ushortb* xl,
                       int fi, float* dest) {
            const ushortb* F1h = FF1 + (size_t)fi*2097152, *F1l = F1h + 1048576;
            const ushortb* F2h = FF2 + (size_t)fi*2097152, *F2l = F2h + 1048576;
            for (int c = 0; c < 2; ++c) {
                size_t ro = (size_t)c * MCr * 512;
                gemm_sp<<<dim3(16, MCr/128),256,0,stream>>>(
                    xh+ro,xl+ro,512,0, F1h,F1l,512,0, nullptr, nullptr,
                    nullptr, MIDh, MIDl, 2048,0, 512, 1);
                gemm_sp<<<dim3(4, MCr/128),256,0,stream>>>(
                    MIDh,MIDl,2048,0, F2h,F2l,2048,0, nullptr, Xin+ro,
                    dest+ro, nullptr,nullptr, 512,0, 2048, 0);
            }
        };

        // ---------------- encoder ----------------
        embed_es<<<TG*2,256,0,stream>>>(xe, me, W_enc_tok, W_enc_tem, XA, SAh, SAl);
        for (int l = 0; l < 2; ++l) {
            attn(XA, SAh, SAl, SAh, SAl, true, l, enc_attn_b + (size_t)l*4*512, TMP);
            decomp512s<<<TG*2,256,0,stream>>>(TMP, XA, SAh, SAl, nullptr);
            ffn(XA, SAh, SAl, l, TMP);
            decomp512s<<<TG*2,256,0,stream>>>(TMP, XA, SAh, SAl, nullptr);
        }
        ln_rows<<<TG,256,0,stream>>>(XA, enc_ln_w, enc_ln_b, TMP);
        colmean_p<<<G*16,256,0,stream>>>(TMP, PC);
        submean_s<<<TG*2,256,0,stream>>>(TMP, PC, nullptr, SEh, SEl);

        // ---------------- decoder prep ----------------
        mean7<<<G*7,256,0,stream>>>(xe, M7);
        decomp7<<<G*28,256,0,stream>>>(xe, M7, SEAS7, TREND7);
        embed_es<<<TG*2,256,0,stream>>>(SEAS7, md, W_dec_tok, W_dec_tem, XA, SAh, SAl);

        // ---------------- decoder layer ----------------
        attn(XA, SAh, SAl, SAh, SAl, true, 2, dec_self_b, TMP);
        decomp512s<<<TG*2,256,0,stream>>>(TMP, XA, SAh, SAl, TT);
        trendconv_acc<<<G*28,256,0,stream>>>(TT, dec_trend_W, TREND7);

        attn(XA, SAh, SAl, SEh, SEl, false, 3, dec_cross_b, TMP);
        decomp512s<<<TG*2,256,0,stream>>>(TMP, XA, SAh, SAl, TT);
        trendconv_acc<<<G*28,256,0,stream>>>(TT, dec_trend_W, TREND7);

        ffn(XA, SAh, SAl, 2, TMP);
        decomp512s<<<TG*2,256,0,stream>>>(TMP, XA, SAh, SAl, TT);
        trendconv_acc<<<G*28,256,0,stream>>>(TT, dec_trend_W, TREND7);

        ln_rows<<<TG,256,0,stream>>>(XA, dec_ln_w, dec_ln_b, TMP);
        colmean_p<<<G*16,256,0,stream>>>(TMP, PC);
        submean_s<<<TG*2,256,0,stream>>>(TMP, PC, TT, nullptr, nullptr);

        final_out<<<G*14,256,0,stream>>>(TT, proj_W, proj_b, TREND7, outg);
    }
}

// Round 7
// 6301.731 us; speedup vs baseline: 2.4538x; 1.3632x over previous
//
#include <hip/hip_runtime.h>

typedef unsigned short ushortb;
typedef __attribute__((ext_vector_type(8))) _Float16 f16x8;
typedef __attribute__((ext_vector_type(4))) float f32x4;

__device__ __forceinline__ float h2f(ushortb u) {
    _Float16 h; __builtin_memcpy(&h, &u, 2); return (float)h;
}
__device__ __forceinline__ ushortb f2h(float f) {
    _Float16 h = (_Float16)f; ushortb u; __builtin_memcpy(&u, &h, 2); return u;
}
__device__ __forceinline__ float gelu_f(float x) {
    return 0.5f * x * (1.0f + erff(x * 0.7071067811865475f));
}

// async global->LDS, 16B per lane; LDS dest = wave-uniform base + lane*16
__device__ __forceinline__ void ld16(const void* g, void* l) {
    __builtin_amdgcn_global_load_lds(
        (const __attribute__((address_space(1))) unsigned int*)g,
        (__attribute__((address_space(3))) unsigned int*)l, 16, 0, 0);
}

// ------------------------------------------------------------------
// 3-term split-fp16 MFMA GEMM (NT): fp32-fidelity. 128x128 tile, BK=32.
// A: Ah/Al rows, lda; B: Bh/Bl rows, ldb. z-batched strides.
// ------------------------------------------------------------------
__launch_bounds__(256)
__global__ void gemm_h3(const ushortb* __restrict__ Ah, const ushortb* __restrict__ Al,
                        int lda, long sA,
                        const ushortb* __restrict__ Bh, const ushortb* __restrict__ Bl,
                        int ldb, long sB,
                        const float* __restrict__ bias, const float* __restrict__ resid,
                        float* __restrict__ Cf, ushortb* __restrict__ Ch, ushortb* __restrict__ Cl,
                        int ldc, long sC, int K, int act)
{
    __shared__ __align__(16) ushortb LDS[16384];   // 4 planes x [128][32]
    const int tid = threadIdx.x;
    const int wv = tid >> 6, ln = tid & 63;
    const int fr = ln & 15, fq = ln >> 4;
    const int m0 = blockIdx.y << 7, n0 = blockIdx.x << 7;
    const int wr = (wv & 1) << 6, wc = (wv >> 1) << 6;
    const size_t zb = blockIdx.z;

    const ushortb* gb; int ld;
    if (wv == 0)      { gb = Ah + zb * (size_t)sA; ld = lda; }
    else if (wv == 1) { gb = Al + zb * (size_t)sA; ld = lda; }
    else if (wv == 2) { gb = Bh + zb * (size_t)sB; ld = ldb; }
    else              { gb = Bl + zb * (size_t)sB; ld = ldb; }
    const int rbase = (wv < 2) ? m0 : n0;
    const ushortb* gp = gb + (size_t)(rbase + (ln >> 2)) * ld + (ln & 3) * 8;
    ushortb* lplane = LDS + wv * 4096;
    const size_t rstep = (size_t)ld << 4;

    f32x4 acc[4][4] = {};
    for (int k0 = 0; k0 < K; k0 += 32) {
        __syncthreads();
        #pragma unroll
        for (int i = 0; i < 8; ++i)
            ld16(gp + (size_t)i * rstep, lplane + i * 512);
        gp += 32;
        __syncthreads();
        f16x8 afh[4], afl[4], bfh[4], bfl[4];
        #pragma unroll
        for (int t = 0; t < 4; ++t) {
            int ra = ((wr + t*16 + fr) << 5) + (fq << 3);
            int rb = ((wc + t*16 + fr) << 5) + (fq << 3);
            afh[t] = *(const f16x8*)(const void*)(LDS + ra);
            afl[t] = *(const f16x8*)(const void*)(LDS + 4096 + ra);
            bfh[t] = *(const f16x8*)(const void*)(LDS + 8192 + rb);
            bfl[t] = *(const f16x8*)(const void*)(LDS + 12288 + rb);
        }
        #pragma unroll
        for (int tm = 0; tm < 4; ++tm)
            #pragma unroll
            for (int tn = 0; tn < 4; ++tn) {
                f32x4 c = acc[tm][tn];
                c = __builtin_amdgcn_mfma_f32_16x16x32_f16(afh[tm], bfh[tn], c, 0, 0, 0);
                c = __builtin_amdgcn_mfma_f32_16x16x32_f16(afl[tm], bfh[tn], c, 0, 0, 0);
                c = __builtin_amdgcn_mfma_f32_16x16x32_f16(afh[tm], bfl[tn], c, 0, 0, 0);
                acc[tm][tn] = c;
            }
    }

    if (Cf)    Cf += zb * (size_t)sC;
    if (resid) resid += zb * (size_t)sC;
    if (Ch) { Ch += zb * (size_t)sC; if (Cl) Cl += zb * (size_t)sC; }
    #pragma unroll
    for (int tm = 0; tm < 4; ++tm)
        #pragma unroll
        for (int tn = 0; tn < 4; ++tn) {
            int row0 = m0 + wr + tm*16 + fq*4;
            int col  = n0 + wc + tn*16 + fr;
            #pragma unroll
            for (int r = 0; r < 4; ++r) {
                float v = acc[tm][tn][r];
                size_t off = (size_t)(row0 + r) * ldc + col;
                if (bias)  v += bias[col];
                if (resid) v += resid[off];
                if (act)   v = gelu_f(v);
                if (Cf) Cf[off] = v;
                if (Ch) {
                    ushortb h = f2h(v); Ch[off] = h;
                    if (Cl) Cl[off] = f2h(v - h2f(h));
                }
            }
        }
}

// ------------------------------------------------------------------
// Single-term fp16 MFMA GEMM (NT). 128x128 tile, BK=32, 2 LDS planes.
// ------------------------------------------------------------------
__launch_bounds__(256)
__global__ void gemm_h1(const ushortb* __restrict__ Ah, int lda, long sA,
                        const ushortb* __restrict__ Bh, int ldb, long sB,
                        const float* __restrict__ bias, const float* __restrict__ resid,
                        float* __restrict__ Cf, ushortb* __restrict__ Ch,
                        int ldc, long sC, int K, int act)
{
    __shared__ __align__(16) ushortb LDS[8192];   // 2 planes x [128][32]
    const int tid = threadIdx.x;
    const int wv = tid >> 6, ln = tid & 63;
    const int fr = ln & 15, fq = ln >> 4;
    const int m0 = blockIdx.y << 7, n0 = blockIdx.x << 7;
    const int wr = (wv & 1) << 6, wc = (wv >> 1) << 6;
    const size_t zb = blockIdx.z;

    const ushortb* gb; int ld; int rb;
    if (wv < 2) { gb = Ah + zb * (size_t)sA; ld = lda; rb = m0; }
    else        { gb = Bh + zb * (size_t)sB; ld = ldb; rb = n0; }
    const int half = wv & 1;
    const ushortb* gp = gb + (size_t)(rb + half*64 + (ln >> 2)) * ld + (ln & 3) * 8;
    ushortb* lp = LDS + (wv >> 1) * 4096 + half * 2048;
    const size_t rstep = (size_t)ld << 4;

    f32x4 acc[4][4] = {};
    for (int k0 = 0; k0 < K; k0 += 32) {
        __syncthreads();
        #pragma unroll
        for (int i = 0; i < 4; ++i)
            ld16(gp + (size_t)i * rstep, lp + i * 512);
        gp += 32;
        __syncthreads();
        f16x8 af[4], bf[4];
        #pragma unroll
        for (int t = 0; t < 4; ++t) {
            int ra = ((wr + t*16 + fr) << 5) + (fq << 3);
            int rx = ((wc + t*16 + fr) << 5) + (fq << 3);
            af[t] = *(const f16x8*)(const void*)(LDS + ra);
            bf[t] = *(const f16x8*)(const void*)(LDS + 4096 + rx);
        }
        #pragma unroll
        for (int tm = 0; tm < 4; ++tm)
            #pragma unroll
            for (int tn = 0; tn < 4; ++tn)
                acc[tm][tn] = __builtin_amdgcn_mfma_f32_16x16x32_f16(af[tm], bf[tn], acc[tm][tn], 0, 0, 0);
    }

    if (Cf)    Cf += zb * (size_t)sC;
    if (resid) resid += zb * (size_t)sC;
    if (Ch)    Ch += zb * (size_t)sC;
    #pragma unroll
    for (int tm = 0; tm < 4; ++tm)
        #pragma unroll
        for (int tn = 0; tn < 4; ++tn) {
            int row0 = m0 + wr + tm*16 + fq*4;
            int col  = n0 + wc + tn*16 + fr;
            #pragma unroll
            for (int r = 0; r < 4; ++r) {
                float v = acc[tm][tn][r];
                size_t off = (size_t)(row0 + r) * ldc + col;
                if (bias)  v += bias[col];
                if (resid) v += resid[off];
                if (act)   v = gelu_f(v);
                if (Cf) Cf[off] = v;
                if (Ch) Ch[off] = f2h(v);
            }
        }
}

// ------------------------------------------------------------------
// QK^T with fused diagonal binning: per-block partial corr bins.
// 3-term split-fp16, z-batched. PBIN[z][64 blocks][1024 tau].
// Deterministic: wave-private LDS bins, fixed program order.
// ------------------------------------------------------------------
__launch_bounds__(256)
__global__ void gemm_corr(const ushortb* __restrict__ Qh, const ushortb* __restrict__ Ql,
                          int ldq, long sQ,
                          const ushortb* __restrict__ Kh, const ushortb* __restrict__ Kl,
                          int ldk, long sK,
                          float* __restrict__ PBIN, int K)
{
    __shared__ __align__(16) ushortb LDS[16384];
    const int tid = threadIdx.x;
    const int wv = tid >> 6, ln = tid & 63;
    const int fr = ln & 15, fq = ln >> 4;
    const int m0 = blockIdx.y << 7, n0 = blockIdx.x << 7;
    const int wr = (wv & 1) << 6, wc = (wv >> 1) << 6;
    const size_t zb = blockIdx.z;

    const ushortb* gb; int ld;
    if (wv == 0)      { gb = Qh + zb * (size_t)sQ; ld = ldq; }
    else if (wv == 1) { gb = Ql + zb * (size_t)sQ; ld = ldq; }
    else if (wv == 2) { gb = Kh + zb * (size_t)sK; ld = ldk; }
    else              { gb = Kl + zb * (size_t)sK; ld = ldk; }
    const int rbase = (wv < 2) ? m0 : n0;
    const ushortb* gp = gb + (size_t)(rbase + (ln >> 2)) * ld + (ln & 3) * 8;
    ushortb* lplane = LDS + wv * 4096;
    const size_t rstep = (size_t)ld << 4;

    f32x4 acc[4][4] = {};
    for (int k0 = 0; k0 < K; k0 += 32) {
        __syncthreads();
        #pragma unroll
        for (int i = 0; i < 8; ++i)
            ld16(gp + (size_t)i * rstep, lplane + i * 512);
        gp += 32;
        __syncthreads();
        f16x8 afh[4], afl[4], bfh[4], bfl[4];
        #pragma unroll
        for (int t = 0; t < 4; ++t) {
            int ra = ((wr + t*16 + fr) << 5) + (fq << 3);
            int rb = ((wc + t*16 + fr) << 5) + (fq << 3);
            afh[t] = *(const f16x8*)(const void*)(LDS + ra);
            afl[t] = *(const f16x8*)(const void*)(LDS + 4096 + ra);
            bfh[t] = *(const f16x8*)(const void*)(LDS + 8192 + rb);
            bfl[t] = *(const f16x8*)(const void*)(LDS + 12288 + rb);
        }
        #pragma unroll
        for (int tm = 0; tm < 4; ++tm)
            #pragma unroll
            for (int tn = 0; tn < 4; ++tn) {
                f32x4 c = acc[tm][tn];
                c = __builtin_amdgcn_mfma_f32_16x16x32_f16(afh[tm], bfh[tn], c, 0, 0, 0);
                c = __builtin_amdgcn_mfma_f32_16x16x32_f16(afl[tm], bfh[tn], c, 0, 0, 0);
                c = __builtin_amdgcn_mfma_f32_16x16x32_f16(afh[tm], bfl[tn], c, 0, 0, 0);
                acc[tm][tn] = c;
            }
    }

    // ---- fused diagonal binning (reuse staging LDS as 4 wave-private bin arrays)
    __syncthreads();
    float* bins = (float*)LDS;           // 4 x 1024 floats = 16KB
    #pragma unroll
    for (int i = 0; i < 16; ++i) bins[tid + (i << 8)] = 0.f;
    __syncthreads();
    float* wb = bins + (wv << 10);
    #pragma unroll
    for (int tm = 0; tm < 4; ++tm)
        #pragma unroll
        for (int tn = 0; tn < 4; ++tn) {
            int row0 = m0 + wr + tm*16 + fq*4;
            int col  = n0 + wc + tn*16 + fr;
            #pragma unroll
            for (int r = 0; r < 4; ++r) {
                int tau = (row0 + r - col) & 1023;
                atomicAdd(&wb[tau], acc[tm][tn][r]);
            }
        }
    __syncthreads();
    size_t blk = (zb << 6) + (blockIdx.y << 3) + blockIdx.x;
    for (int i = tid; i < 1024; i += 256)
        PBIN[(blk << 10) + i] = (bins[i] + bins[1024 + i]) + (bins[2048 + i] + bins[3072 + i]);
}

// CORR[b][tau] = (1/512) * sum over 64 block partials
__launch_bounds__(256)
__global__ void corr_sum(const float* __restrict__ PBIN, float* __restrict__ CORR)
{
    int idx = blockIdx.x * 256 + threadIdx.x;   // G*1024
    int b = idx >> 10, tau = idx & 1023;
    const float* p = PBIN + ((size_t)b << 16) + tau;
    float s = 0.f;
    #pragma unroll
    for (int ch = 0; ch < 64; ++ch) s += p[ch << 10];
    CORR[idx] = s * (1.f / 512.f);
}

// top-6 + softmax per local batch from CORR
__launch_bounds__(256)
__global__ void topk6(const float* __restrict__ CORR, int* __restrict__ DELAY,
                      float* __restrict__ WGT)
{
    __shared__ float v[1024];
    __shared__ float rv[256];
    __shared__ int   ri[256];
    __shared__ float wv6[6];
    __shared__ int   wi6[6];
    const int b = blockIdx.x, tid = threadIdx.x;
    #pragma unroll
    for (int k = 0; k < 4; ++k) { int tau = tid + (k<<8); v[tau] = CORR[b*1024 + tau]; }
    __syncthreads();
    for (int it = 0; it < 6; ++it) {
        float best = v[tid]; int bi = tid;
        #pragma unroll
        for (int k = 1; k < 4; ++k) {
            int i = tid + (k << 8);
            float xv = v[i];
            if (xv > best) { best = xv; bi = i; }
        }
        rv[tid] = best; ri[tid] = bi;
        __syncthreads();
        for (int s = 128; s > 0; s >>= 1) {
            if (tid < s) {
                if (rv[tid+s] > rv[tid] || (rv[tid+s] == rv[tid] && ri[tid+s] < ri[tid])) {
                    rv[tid] = rv[tid+s]; ri[tid] = ri[tid+s];
                }
            }
            __syncthreads();
        }
        if (tid == 0) { wv6[it] = rv[0]; wi6[it] = ri[0]; v[ri[0]] = -1e30f; }
        __syncthreads();
    }
    if (tid == 0) {
        float mx = wv6[0], s = 0.f, e[6];
        #pragma unroll
        for (int i = 0; i < 6; ++i) { e[i] = expf(wv6[i] - mx); s += e[i]; }
        #pragma unroll
        for (int i = 0; i < 6; ++i) { WGT[b*6+i] = e[i]/s; DELAY[b*6+i] = wi6[i]; }
    }
}

// gather from V plane (fp16, cols 1024.. of QKV, row stride 1536) -> fp16 out
__launch_bounds__(256)
__global__ void gather6m(const ushortb* __restrict__ Vh, const int* __restrict__ DELAY,
                         const float* __restrict__ WGT, ushortb* __restrict__ Gh)
{
    int idx = blockIdx.x * 256 + threadIdx.x;     // TG*128 threads
    int d0 = (idx & 127) << 2, bt = idx >> 7, t = bt & 1023, b = bt >> 10;
    const size_t bo = (size_t)b * 1024 * 1536;
    float a0=0,a1=0,a2=0,a3=0;
    #pragma unroll
    for (int i = 0; i < 6; ++i) {
        int s = (t + DELAY[b*6+i]) & 1023;
        float w = WGT[b*6+i];
        const ushortb* vp = Vh + bo + (size_t)s * 1536 + d0;
        uint2 hv = *(const uint2*)vp;
        a0 += w * h2f((ushortb)(hv.x & 0xFFFFu));
        a1 += w * h2f((ushortb)(hv.x >> 16));
        a2 += w * h2f((ushortb)(hv.y & 0xFFFFu));
        a3 += w * h2f((ushortb)(hv.y >> 16));
    }
    uint2 op;
    op.x = (unsigned)f2h(a0) | ((unsigned)f2h(a1) << 16);
    op.y = (unsigned)f2h(a2) | ((unsigned)f2h(a3) << 16);
    *(uint2*)(Gh + ((size_t)bt << 9) + d0) = op;
}

// series_decomp + fused fp16 split; T: tmode 0=skip 1=set 2=accumulate
__launch_bounds__(256)
__global__ void decomp512s(const float* __restrict__ X, float* __restrict__ S,
                           ushortb* __restrict__ Sh, ushortb* __restrict__ Sl,
                           float* __restrict__ T, int tmode)
{
    int idx = blockIdx.x * 256 + threadIdx.x;     // TG*512
    int d = idx & 511, bt = idx >> 9, t = bt & 1023;
    int base = bt - t;
    const float* Xb = X + ((size_t)base << 9) + d;
    float s = 0.f;
    #pragma unroll
    for (int w = -12; w <= 12; ++w) {
        int tt = t + w; tt = tt < 0 ? 0 : (tt > 1023 ? 1023 : tt);
        s += Xb[tt << 9];
    }
    float m = s * (1.f / 25.f);
    float v = X[idx] - m;
    S[idx] = v;
    ushortb h = f2h(v);
    Sh[idx] = h; Sl[idx] = f2h(v - h2f(h));
    if (tmode == 1) T[idx] = m;
    else if (tmode == 2) T[idx] += m;
}

__launch_bounds__(256)
__global__ void ln_rows(const float* __restrict__ X, const float* __restrict__ w,
                        const float* __restrict__ bias, float* __restrict__ Y)
{
    __shared__ float r1[256], r2[256];
    const int row = blockIdx.x, tid = threadIdx.x;
    const float* xr = X + (size_t)row * 512;
    float x0 = xr[tid], x1 = xr[tid + 256];
    r1[tid] = x0 + x1; r2[tid] = x0*x0 + x1*x1;
    __syncthreads();
    for (int s = 128; s > 0; s >>= 1) {
        if (tid < s) { r1[tid] += r1[tid+s]; r2[tid] += r2[tid+s]; }
        __syncthreads();
    }
    float mu = r1[0] * (1.f/512.f);
    float var = r2[0] * (1.f/512.f) - mu*mu;
    float rstd = rsqrtf(var + 1e-5f);
    float* yr = Y + (size_t)row * 512;
    yr[tid]       = (x0 - mu) * rstd * w[tid]     + bias[tid];
    yr[tid + 256] = (x1 - mu) * rstd * w[tid+256] + bias[tid+256];
}

__launch_bounds__(256)
__global__ void colmean_p(const float* __restrict__ Y, float* __restrict__ PC)
{
    int i = blockIdx.x * 256 + threadIdx.x;   // G*4096
    int b = i >> 12, r = i & 4095, d = r >> 3, c = r & 7;
    const float* p = Y + ((size_t)b << 19) + ((size_t)(c << 7) << 9) + d;
    float s = 0.f;
    for (int t = 0; t < 128; ++t) s += p[t << 9];
    PC[i] = s * (1.f/1024.f);
}

__launch_bounds__(256)
__global__ void submean_s(const float* __restrict__ Y, const float* __restrict__ PC,
                          float* __restrict__ Zf, ushortb* __restrict__ Zh,
                          ushortb* __restrict__ Zl)
{
    int idx = blockIdx.x * 256 + threadIdx.x;
    int d = idx & 511, b = idx >> 19;
    const float* pc = PC + ((size_t)b << 12) + (d << 3);
    float m = ((pc[0]+pc[1])+(pc[2]+pc[3]))+((pc[4]+pc[5])+(pc[6]+pc[7]));
    float v = Y[idx] - m;
    if (Zf) Zf[idx] = v;
    if (Zh) { ushortb h = f2h(v); Zh[idx] = h; Zl[idx] = f2h(v - h2f(h)); }
}

__launch_bounds__(256)
__global__ void embed_es(const float* __restrict__ x, const float* __restrict__ mark,
                         const float* __restrict__ Wtok, const float* __restrict__ Wtem,
                         float* __restrict__ out, ushortb* __restrict__ Oh,
                         ushortb* __restrict__ Ol)
{
    int idx = blockIdx.x * 256 + threadIdx.x;
    int d = idx & 511, bt = idx >> 9, t = bt & 1023, b = bt >> 10;
    float acc = 0.f;
    #pragma unroll
    for (int j = 0; j < 3; ++j) {
        int tt = (t + 1023 + j) & 1023;
        const float* xr = x + (size_t)(b*1024 + tt)*7;
        #pragma unroll
        for (int c = 0; c < 7; ++c)
            acc += xr[c] * Wtok[(j*7+c)*512 + d];
    }
    const float* mr = mark + (size_t)bt*4;
    #pragma unroll
    for (int m = 0; m < 4; ++m) acc += mr[m] * Wtem[m*512 + d];
    out[idx] = acc;
    ushortb h = f2h(acc);
    Oh[idx] = h; Ol[idx] = f2h(acc - h2f(h));
}

__launch_bounds__(256)
__global__ void mean7(const float* __restrict__ x, float* __restrict__ M7)
{
    __shared__ float r[256];
    int bc = blockIdx.x, b = bc / 7, c = bc % 7, tid = threadIdx.x;
    float s = 0.f;
    for (int t = tid; t < 1024; t += 256) s += x[(size_t)(b*1024+t)*7 + c];
    r[tid] = s; __syncthreads();
    for (int st = 128; st > 0; st >>= 1) { if (tid < st) r[tid] += r[tid+st]; __syncthreads(); }
    if (tid == 0) M7[bc] = r[0] * (1.f/1024.f);
}

__launch_bounds__(256)
__global__ void decomp7(const float* __restrict__ x, const float* __restrict__ M7,
                        float* __restrict__ SEAS7, float* __restrict__ TREND7)
{
    int idx = blockIdx.x * 256 + threadIdx.x;  // TG*7
    int c = idx % 7, bt = idx / 7, t = bt & 1023, b = bt >> 10;
    if (t < 512) {
        int s0 = t + 512;
        float s = 0.f;
        #pragma unroll
        for (int w = -12; w <= 12; ++w) {
            int tt = s0 + w; tt = tt < 0 ? 0 : (tt > 1023 ? 1023 : tt);
            s += x[(size_t)(b*1024+tt)*7 + c];
        }
        float m = s * (1.f/25.f);
        SEAS7[idx] = x[(size_t)(b*1024+s0)*7 + c] - m;
        TREND7[idx] = m;
    } else {
        SEAS7[idx] = 0.f;
        TREND7[idx] = M7[b*7 + c];
    }
}

// TREND7 += circ_conv3(T) for output rows t in [512,1024) only
__launch_bounds__(256)
__global__ void trendconv_half(const float* __restrict__ T, const float* __restrict__ W,
                               float* __restrict__ TREND7)
{
    int idx = blockIdx.x * 256 + threadIdx.x;  // G*512*7
    int co = idx % 7, btt = idx / 7, tt = btt & 511, b = btt >> 9;
    int t = tt + 512;
    float acc = 0.f;
    for (int j = 0; j < 3; ++j) {
        int t2 = (t + 1023 + j) & 1023;
        const float* r = T + ((size_t)(b*1024 + t2) << 9);
        const float* wj = W + j*512*7 + co;
        for (int c = 0; c < 512; ++c) acc += r[c] * wj[c*7];
    }
    TREND7[(size_t)(b*1024 + t)*7 + co] += acc;
}

__launch_bounds__(256)
__global__ void final_out(const float* __restrict__ X, const float* __restrict__ PW,
                          const float* __restrict__ PB, const float* __restrict__ TREND7,
                          float* __restrict__ out)
{
    int idx = blockIdx.x * 256 + threadIdx.x;  // G*512*7
    int c = idx % 7, btt = idx / 7, tt = btt & 511, b = btt >> 9;
    int t = tt + 512;
    float acc = PB[c] + TREND7[(size_t)(b*1024 + t)*7 + c];
    const float* xr = X + ((size_t)(b*1024 + t) << 9);
    for (int d = 0; d < 512; ++d) acc += xr[d] * PW[d*7 + c];
    out[idx] = acc;
}

// attn weight transpose+split into pooled layout (per block a, 1572864 elems):
// QKh@0 (1024x512), QKl@524288, Vh@1048576, Oh@1310720 (V,O single fp16)
__launch_bounds__(256)
__global__ void wsplit_att(const float* __restrict__ W, ushortb* __restrict__ pool, int which)
{
    __shared__ float t[32][33];
    const int m = blockIdx.z;
    const int kb = blockIdx.y << 5, nb = blockIdx.x << 5;
    const int c = threadIdx.x & 31, rr = threadIdx.x >> 5;
    const float* Wm = W + (size_t)m * 262144;
    #pragma unroll
    for (int i = 0; i < 4; ++i)
        t[rr + i*8][c] = Wm[(size_t)(kb + rr + i*8) * 512 + nb + c];
    __syncthreads();
    const int a = (which == 0) ? (m >> 2) : (which + 1);
    const int j = (which == 0) ? (m & 3) : m;
    size_t hi, lo; bool haslo;
    if (j == 0)      { hi = 0;       lo = 524288; haslo = true; }
    else if (j == 1) { hi = 262144;  lo = 786432; haslo = true; }
    else if (j == 2) { hi = 1048576; lo = 0; haslo = false; }
    else             { hi = 1310720; lo = 0; haslo = false; }
    ushortb* pb = pool + (size_t)a * 1572864;
    #pragma unroll
    for (int i = 0; i < 4; ++i) {
        int n = nb + rr + i*8, k = kb + c;
        float v = t[c][rr + i*8];
        ushortb h = f2h(v);
        pb[hi + (size_t)n * 512 + k] = h;
        if (haslo) pb[lo + (size_t)n * 512 + k] = f2h(v - h2f(h));
    }
}

// FF transpose, single fp16: src mat m [K,N] -> dest + m*1048576, [N,K]
__launch_bounds__(256)
__global__ void wsplit_ff(const float* __restrict__ W, ushortb* __restrict__ dh,
                          int K, int N)
{
    __shared__ float t[32][33];
    const int m = blockIdx.z;
    const int kb = blockIdx.y << 5, nb = blockIdx.x << 5;
    const int c = threadIdx.x & 31, rr = threadIdx.x >> 5;
    const float* Wm = W + (size_t)m * K * N;
    #pragma unroll
    for (int i = 0; i < 4; ++i)
        t[rr + i*8][c] = Wm[(size_t)(kb + rr + i*8) * N + nb + c];
    __syncthreads();
    ushortb* Dh = dh + (size_t)m * 1048576;
    #pragma unroll
    for (int i = 0; i < 4; ++i) {
        int n = nb + rr + i*8, k = kb + c;
        Dh[(size_t)n * K + k] = f2h(t[c][rr + i*8]);
    }
}

__launch_bounds__(256)
__global__ void sentinel(float* __restrict__ out, int n)
{
    int i = blockIdx.x * 256 + threadIdx.x;
    if (i < n) out[i] = -54321.0f;
}

// ------------------------------------------------------------------
extern "C" void kernel_launch(void* const* d_in, const int* in_sizes, int n_in,
                              void* d_out, int out_size, void* d_ws, size_t ws_size,
                              hipStream_t stream)
{
    const float* x_enc      = (const float*)d_in[0];
    const float* x_mark_enc = (const float*)d_in[1];
    const float* x_mark_dec = (const float*)d_in[3];
    const float* W_enc_tok  = (const float*)d_in[4];
    const float* W_enc_tem  = (const float*)d_in[5];
    const float* W_dec_tok  = (const float*)d_in[6];
    const float* W_dec_tem  = (const float*)d_in[7];
    const float* enc_attn_W = (const float*)d_in[8];
    const float* enc_attn_b = (const float*)d_in[9];
    const float* enc_ff1    = (const float*)d_in[10];
    const float* enc_ff2    = (const float*)d_in[11];
    const float* enc_ln_w   = (const float*)d_in[12];
    const float* enc_ln_b   = (const float*)d_in[13];
    const float* dec_self_W = (const float*)d_in[14];
    const float* dec_self_b = (const float*)d_in[15];
    const float* dec_cross_W= (const float*)d_in[16];
    const float* dec_cross_b= (const float*)d_in[17];
    const float* dec_ff1    = (const float*)d_in[18];
    const float* dec_ff2    = (const float*)d_in[19];
    const float* dec_trend_W= (const float*)d_in[20];
    const float* dec_ln_w   = (const float*)d_in[21];
    const float* dec_ln_b   = (const float*)d_in[22];
    const float* proj_W     = (const float*)d_in[23];
    const float* proj_b     = (const float*)d_in[24];
    float* out = (float*)d_out;

    const size_t ATT_E = (size_t)4 * 1572864;
    const size_t FF_E  = (size_t)3 * 1048576;
    const size_t WBYTES = (ATT_E + 2 * FF_E) * 2 + 4096;

    auto need = [&](long g) -> size_t {
        size_t TGl = (size_t)g * 1024;
        size_t acts  = 3 * TGl * 512 * 4;         // XA, TMP, TT
        size_t pairs = 4 * TGl * 512 * 2;         // SAh,SAl,SEh,SEl
        size_t r1    = TGl * 6144;                // QKV hi+lo / MID
        size_t sg    = TGl * 1024;                // SGh
        size_t pbin  = (size_t)g * 65536 * 4;
        size_t misc  = (size_t)g * (1024 + 4096 + 7 + 2*7168 + 16) * 4 + 65536;
        return WBYTES + acts + pairs + r1 + sg + pbin + misc + 16384;
    };
    int G = 0;
    for (int g = 32; g >= 1; g >>= 1) if (need(g) <= ws_size) { G = g; break; }
    if (G == 0) {
        sentinel<<<(out_size + 255) / 256, 256, 0, stream>>>(out, out_size);
        return;
    }
    const int TG = G * 1024;

    char* p = (char*)d_ws;
    auto carve = [&](size_t bytes) -> char* {
        char* r = p; p += (bytes + 255) & ~(size_t)255; return r;
    };
    ushortb* ATT = (ushortb*)carve(ATT_E * 2);
    ushortb* FF1 = (ushortb*)carve(FF_E * 2);
    ushortb* FF2 = (ushortb*)carve(FF_E * 2);

    const size_t ACTB = (size_t)TG * 512 * 4;
    const size_t SPLB = (size_t)TG * 512 * 2;
    float* XA  = (float*)carve(ACTB);
    float* TMP = (float*)carve(ACTB);
    float* TT  = (float*)carve(ACTB);
    ushortb* SAh = (ushortb*)carve(SPLB);
    ushortb* SAl = (ushortb*)carve(SPLB);
    ushortb* SEh = (ushortb*)carve(SPLB);
    ushortb* SEl = (ushortb*)carve(SPLB);
    char* R1 = carve((size_t)TG * 6144);             // QKV pair / MID
    ushortb* SGh = (ushortb*)carve(SPLB);
    float* PBIN  = (float*)carve((size_t)G * 65536 * 4);
    float* CORR  = (float*)carve((size_t)G * 1024 * 4);
    float* PC    = (float*)carve((size_t)G * 4096 * 4);
    float* M7    = (float*)carve((size_t)G * 7 * 4);
    float* SEAS7 = (float*)carve((size_t)G * 1024 * 7 * 4);
    float* TREND7= (float*)carve((size_t)G * 1024 * 7 * 4);
    float* WGT   = (float*)carve((size_t)G * 6 * 4);
    int*   DELAY = (int*)  carve((size_t)G * 6 * 4);

    ushortb* QKVh = (ushortb*)R1;
    ushortb* QKVl = QKVh + (size_t)TG * 1536;
    ushortb* MIDh = (ushortb*)R1;

    // ---- weight transforms ----
    wsplit_att<<<dim3(16,16,8),256,0,stream>>>(enc_attn_W, ATT, 0);
    wsplit_att<<<dim3(16,16,4),256,0,stream>>>(dec_self_W, ATT, 1);
    wsplit_att<<<dim3(16,16,4),256,0,stream>>>(dec_cross_W, ATT, 2);
    wsplit_ff<<<dim3(64,16,2),256,0,stream>>>(enc_ff1, FF1, 512, 2048);
    wsplit_ff<<<dim3(64,16,1),256,0,stream>>>(dec_ff1, FF1 + (size_t)2*1048576, 512, 2048);
    wsplit_ff<<<dim3(16,64,2),256,0,stream>>>(enc_ff2, FF2, 2048, 512);
    wsplit_ff<<<dim3(16,64,1),256,0,stream>>>(dec_ff2, FF2 + (size_t)2*1048576, 2048, 512);

    for (int g0 = 0; g0 < 32; g0 += G) {
        const float* xe  = x_enc      + (size_t)g0 * 1024 * 7;
        const float* me  = x_mark_enc + (size_t)g0 * 1024 * 4;
        const float* md  = x_mark_dec + (size_t)g0 * 1024 * 4;
        float*       outg= out        + (size_t)g0 * 512 * 7;

        auto corr_gather_oproj = [&](const float* Xq, const ushortb* base,
                                     const float* bv, float* dest) {
            gemm_corr<<<dim3(8,8,G),256,0,stream>>>(
                QKVh,QKVl,1536,(long)1024*1536, QKVh+512,QKVl+512,1536,(long)1024*1536,
                PBIN, 512);
            corr_sum<<<G*4,256,0,stream>>>(PBIN, CORR);
            topk6<<<G,256,0,stream>>>(CORR, DELAY, WGT);
            gather6m<<<TG/2,256,0,stream>>>(QKVh+1024, DELAY, WGT, SGh);
            gemm_h1<<<dim3(4, TG/128),256,0,stream>>>(
                SGh,512,0, base+1310720,512,0, bv+1536, Xq, dest, nullptr, 512,0, 512, 0);
        };
        auto attn_self = [&](const float* Xq, const ushortb* xh, const ushortb* xl,
                             int a, const float* bv, float* dest) {
            const ushortb* base = ATT + (size_t)a * 1572864;
            gemm_h3<<<dim3(8, TG/128),256,0,stream>>>(
                xh,xl,512,0, base,base+524288,512,0, bv, nullptr,
                nullptr, QKVh,QKVl, 1536,0, 512, 0);
            gemm_h1<<<dim3(4, TG/128),256,0,stream>>>(
                xh,512,0, base+1048576,512,0, bv+1024, nullptr,
                nullptr, QKVh+1024, 1536,0, 512, 0);
            corr_gather_oproj(Xq, base, bv, dest);
        };
        auto attn_cross = [&](const float* Xq, const ushortb* qh, const ushortb* ql,
                              const ushortb* kvh, const ushortb* kvl,
                              int a, const float* bv, float* dest) {
            const ushortb* base = ATT + (size_t)a * 1572864;
            gemm_h3<<<dim3(4, TG/128),256,0,stream>>>(
                qh,ql,512,0, base,base+524288,512,0, bv, nullptr,
                nullptr, QKVh,QKVl, 1536,0, 512, 0);
            gemm_h3<<<dim3(4, TG/128),256,0,stream>>>(
                kvh,kvl,512,0, base+262144,base+786432,512,0, bv+512, nullptr,
                nullptr, QKVh+512,QKVl+512, 1536,0, 512, 0);
            gemm_h1<<<dim3(4, TG/128),256,0,stream>>>(
                kvh,512,0, base+1048576,512,0, bv+1024, nullptr,
                nullptr, QKVh+1024, 1536,0, 512, 0);
            corr_gather_oproj(Xq, base, bv, dest);
        };
        auto ffn = [&](const float* Xin, const ushortb* xh, int fi, float* dest) {
            gemm_h1<<<dim3(16, TG/128),256,0,stream>>>(
                xh,512,0, FF1 + (size_t)fi*1048576,512,0, nullptr, nullptr,
                nullptr, MIDh, 2048,0, 512, 1);
            gemm_h1<<<dim3(4, TG/128),256,0,stream>>>(
                MIDh,2048,0, FF2 + (size_t)fi*1048576,2048,0, nullptr, Xin,
                dest, nullptr, 512,0, 2048, 0);
        };

        // ---------------- encoder ----------------
        embed_es<<<TG*2,256,0,stream>>>(xe, me, W_enc_tok, W_enc_tem, XA, SAh, SAl);
        for (int l = 0; l < 2; ++l) {
            attn_self(XA, SAh, SAl, l, enc_attn_b + (size_t)l*4*512, TMP);
            decomp512s<<<TG*2,256,0,stream>>>(TMP, XA, SAh, SAl, nullptr, 0);
            ffn(XA, SAh, l, TMP);
            decomp512s<<<TG*2,256,0,stream>>>(TMP, XA, SAh, SAl, nullptr, 0);
        }
        ln_rows<<<TG,256,0,stream>>>(XA, enc_ln_w, enc_ln_b, TMP);
        colmean_p<<<G*16,256,0,stream>>>(TMP, PC);
        submean_s<<<TG*2,256,0,stream>>>(TMP, PC, nullptr, SEh, SEl);

        // ---------------- decoder prep ----------------
        mean7<<<G*7,256,0,stream>>>(xe, M7);
        decomp7<<<G*28,256,0,stream>>>(xe, M7, SEAS7, TREND7);
        embed_es<<<TG*2,256,0,stream>>>(SEAS7, md, W_dec_tok, W_dec_tem, XA, SAh, SAl);

        // ---------------- decoder layer ----------------
        attn_self(XA, SAh, SAl, 2, dec_self_b, TMP);
        decomp512s<<<TG*2,256,0,stream>>>(TMP, XA, SAh, SAl, TT, 1);

        attn_cross(XA, SAh, SAl, SEh, SEl, 3, dec_cross_b, TMP);
        decomp512s<<<TG*2,256,0,stream>>>(TMP, XA, SAh, SAl, TT, 2);

        ffn(XA, SAh, 2, TMP);
        decomp512s<<<TG*2,256,0,stream>>>(TMP, XA, SAh, SAl, TT, 2);

        trendconv_half<<<G*14,256,0,stream>>>(TT, dec_trend_W, TREND7);

        ln_rows<<<TG,256,0,stream>>>(XA, dec_ln_w, dec_ln_b, TMP);
        colmean_p<<<G*16,256,0,stream>>>(TMP, PC);
        submean_s<<<TG*2,256,0,stream>>>(TMP, PC, TT, nullptr, nullptr);

        final_out<<<G*14,256,0,stream>>>(TT, proj_W, proj_b, TREND7, outg);
    }
}

// Round 8
// 5238.873 us; speedup vs baseline: 2.9516x; 1.2029x over previous
//
#include <hip/hip_runtime.h>

typedef unsigned short ushortb;
typedef __attribute__((ext_vector_type(8))) _Float16 f16x8;
typedef __attribute__((ext_vector_type(4))) float f32x4;

__device__ __forceinline__ float h2f(ushortb u) {
    _Float16 h; __builtin_memcpy(&h, &u, 2); return (float)h;
}
__device__ __forceinline__ ushortb f2h(float f) {
    _Float16 h = (_Float16)f; ushortb u; __builtin_memcpy(&u, &h, 2); return u;
}
__device__ __forceinline__ float gelu_f(float x) {
    return 0.5f * x * (1.0f + erff(x * 0.7071067811865475f));
}

__device__ __forceinline__ void ld16(const void* g, void* l) {
    __builtin_amdgcn_global_load_lds(
        (const __attribute__((address_space(1))) unsigned int*)g,
        (__attribute__((address_space(3))) unsigned int*)l, 16, 0, 0);
}

// ------------------------------------------------------------------
// 3-term split-fp16 MFMA GEMM (NT), pair in -> pair out (fp32 fidelity)
// ------------------------------------------------------------------
__launch_bounds__(256)
__global__ void gemm_h3(const ushortb* __restrict__ Ah, const ushortb* __restrict__ Al,
                        int lda,
                        const ushortb* __restrict__ Bh, const ushortb* __restrict__ Bl,
                        int ldb,
                        const float* __restrict__ bias,
                        ushortb* __restrict__ Ch, ushortb* __restrict__ Cl, int ldc, int K)
{
    __shared__ __align__(16) ushortb LDS[16384];
    const int tid = threadIdx.x;
    const int wv = tid >> 6, ln = tid & 63;
    const int fr = ln & 15, fq = ln >> 4;
    const int m0 = blockIdx.y << 7, n0 = blockIdx.x << 7;
    const int wr = (wv & 1) << 6, wc = (wv >> 1) << 6;

    const ushortb* gb; int ld;
    if (wv == 0)      { gb = Ah; ld = lda; }
    else if (wv == 1) { gb = Al; ld = lda; }
    else if (wv == 2) { gb = Bh; ld = ldb; }
    else              { gb = Bl; ld = ldb; }
    const int rbase = (wv < 2) ? m0 : n0;
    const ushortb* gp = gb + (size_t)(rbase + (ln >> 2)) * ld + (ln & 3) * 8;
    ushortb* lplane = LDS + wv * 4096;
    const size_t rstep = (size_t)ld << 4;

    f32x4 acc[4][4] = {};
    for (int k0 = 0; k0 < K; k0 += 32) {
        __syncthreads();
        #pragma unroll
        for (int i = 0; i < 8; ++i)
            ld16(gp + (size_t)i * rstep, lplane + i * 512);
        gp += 32;
        __syncthreads();
        f16x8 afh[4], afl[4], bfh[4], bfl[4];
        #pragma unroll
        for (int t = 0; t < 4; ++t) {
            int ra = ((wr + t*16 + fr) << 5) + (fq << 3);
            int rb = ((wc + t*16 + fr) << 5) + (fq << 3);
            afh[t] = *(const f16x8*)(const void*)(LDS + ra);
            afl[t] = *(const f16x8*)(const void*)(LDS + 4096 + ra);
            bfh[t] = *(const f16x8*)(const void*)(LDS + 8192 + rb);
            bfl[t] = *(const f16x8*)(const void*)(LDS + 12288 + rb);
        }
        #pragma unroll
        for (int tm = 0; tm < 4; ++tm)
            #pragma unroll
            for (int tn = 0; tn < 4; ++tn) {
                f32x4 c = acc[tm][tn];
                c = __builtin_amdgcn_mfma_f32_16x16x32_f16(afh[tm], bfh[tn], c, 0, 0, 0);
                c = __builtin_amdgcn_mfma_f32_16x16x32_f16(afl[tm], bfh[tn], c, 0, 0, 0);
                c = __builtin_amdgcn_mfma_f32_16x16x32_f16(afh[tm], bfl[tn], c, 0, 0, 0);
                acc[tm][tn] = c;
            }
    }
    #pragma unroll
    for (int tm = 0; tm < 4; ++tm)
        #pragma unroll
        for (int tn = 0; tn < 4; ++tn) {
            int row0 = m0 + wr + tm*16 + fq*4;
            int col  = n0 + wc + tn*16 + fr;
            #pragma unroll
            for (int r = 0; r < 4; ++r) {
                float v = acc[tm][tn][r];
                if (bias) v += bias[col];
                size_t off = (size_t)(row0 + r) * ldc + col;
                ushortb h = f2h(v);
                Ch[off] = h; Cl[off] = f2h(v - h2f(h));
            }
        }
}

// ------------------------------------------------------------------
// Single-term fp16 MFMA GEMM (NT); optional pair resid, pair/single out
// ------------------------------------------------------------------
__launch_bounds__(256)
__global__ void gemm_h1(const ushortb* __restrict__ Ah, int lda,
                        const ushortb* __restrict__ Bh, int ldb,
                        const float* __restrict__ bias,
                        const ushortb* __restrict__ Rh, const ushortb* __restrict__ Rl,
                        ushortb* __restrict__ Ch, ushortb* __restrict__ Cl,
                        int ldc, int K, int act)
{
    __shared__ __align__(16) ushortb LDS[8192];
    const int tid = threadIdx.x;
    const int wv = tid >> 6, ln = tid & 63;
    const int fr = ln & 15, fq = ln >> 4;
    const int m0 = blockIdx.y << 7, n0 = blockIdx.x << 7;
    const int wr = (wv & 1) << 6, wc = (wv >> 1) << 6;

    const ushortb* gb; int ld; int rb;
    if (wv < 2) { gb = Ah; ld = lda; rb = m0; }
    else        { gb = Bh; ld = ldb; rb = n0; }
    const int half = wv & 1;
    const ushortb* gp = gb + (size_t)(rb + half*64 + (ln >> 2)) * ld + (ln & 3) * 8;
    ushortb* lp = LDS + (wv >> 1) * 4096 + half * 2048;
    const size_t rstep = (size_t)ld << 4;

    f32x4 acc[4][4] = {};
    for (int k0 = 0; k0 < K; k0 += 32) {
        __syncthreads();
        #pragma unroll
        for (int i = 0; i < 4; ++i)
            ld16(gp + (size_t)i * rstep, lp + i * 512);
        gp += 32;
        __syncthreads();
        f16x8 af[4], bf[4];
        #pragma unroll
        for (int t = 0; t < 4; ++t) {
            int ra = ((wr + t*16 + fr) << 5) + (fq << 3);
            int rx = ((wc + t*16 + fr) << 5) + (fq << 3);
            af[t] = *(const f16x8*)(const void*)(LDS + ra);
            bf[t] = *(const f16x8*)(const void*)(LDS + 4096 + rx);
        }
        #pragma unroll
        for (int tm = 0; tm < 4; ++tm)
            #pragma unroll
            for (int tn = 0; tn < 4; ++tn)
                acc[tm][tn] = __builtin_amdgcn_mfma_f32_16x16x32_f16(af[tm], bf[tn], acc[tm][tn], 0, 0, 0);
    }
    #pragma unroll
    for (int tm = 0; tm < 4; ++tm)
        #pragma unroll
        for (int tn = 0; tn < 4; ++tn) {
            int row0 = m0 + wr + tm*16 + fq*4;
            int col  = n0 + wc + tn*16 + fr;
            #pragma unroll
            for (int r = 0; r < 4; ++r) {
                float v = acc[tm][tn][r];
                size_t off = (size_t)(row0 + r) * ldc + col;
                if (bias) v += bias[col];
                if (Rh)   v += h2f(Rh[off]) + h2f(Rl[off]);
                if (act)  v = gelu_f(v);
                ushortb h = f2h(v);
                Ch[off] = h;
                if (Cl) Cl[off] = f2h(v - h2f(h));
            }
        }
}

// ------------------------------------------------------------------
// QK^T with fused diagonal binning (3-term). PBIN[z][64][1024].
// ------------------------------------------------------------------
__launch_bounds__(256)
__global__ void gemm_corr(const ushortb* __restrict__ Qh, const ushortb* __restrict__ Ql,
                          int ldq, long sQ,
                          const ushortb* __restrict__ Kh, const ushortb* __restrict__ Kl,
                          int ldk, long sK,
                          float* __restrict__ PBIN, int K)
{
    __shared__ __align__(16) ushortb LDS[16384];
    const int tid = threadIdx.x;
    const int wv = tid >> 6, ln = tid & 63;
    const int fr = ln & 15, fq = ln >> 4;
    const int m0 = blockIdx.y << 7, n0 = blockIdx.x << 7;
    const int wr = (wv & 1) << 6, wc = (wv >> 1) << 6;
    const size_t zb = blockIdx.z;

    const ushortb* gb; int ld;
    if (wv == 0)      { gb = Qh + zb * (size_t)sQ; ld = ldq; }
    else if (wv == 1) { gb = Ql + zb * (size_t)sQ; ld = ldq; }
    else if (wv == 2) { gb = Kh + zb * (size_t)sK; ld = ldk; }
    else              { gb = Kl + zb * (size_t)sK; ld = ldk; }
    const int rbase = (wv < 2) ? m0 : n0;
    const ushortb* gp = gb + (size_t)(rbase + (ln >> 2)) * ld + (ln & 3) * 8;
    ushortb* lplane = LDS + wv * 4096;
    const size_t rstep = (size_t)ld << 4;

    f32x4 acc[4][4] = {};
    for (int k0 = 0; k0 < K; k0 += 32) {
        __syncthreads();
        #pragma unroll
        for (int i = 0; i < 8; ++i)
            ld16(gp + (size_t)i * rstep, lplane + i * 512);
        gp += 32;
        __syncthreads();
        f16x8 afh[4], afl[4], bfh[4], bfl[4];
        #pragma unroll
        for (int t = 0; t < 4; ++t) {
            int ra = ((wr + t*16 + fr) << 5) + (fq << 3);
            int rb = ((wc + t*16 + fr) << 5) + (fq << 3);
            afh[t] = *(const f16x8*)(const void*)(LDS + ra);
            afl[t] = *(const f16x8*)(const void*)(LDS + 4096 + ra);
            bfh[t] = *(const f16x8*)(const void*)(LDS + 8192 + rb);
            bfl[t] = *(const f16x8*)(const void*)(LDS + 12288 + rb);
        }
        #pragma unroll
        for (int tm = 0; tm < 4; ++tm)
            #pragma unroll
            for (int tn = 0; tn < 4; ++tn) {
                f32x4 c = acc[tm][tn];
                c = __builtin_amdgcn_mfma_f32_16x16x32_f16(afh[tm], bfh[tn], c, 0, 0, 0);
                c = __builtin_amdgcn_mfma_f32_16x16x32_f16(afl[tm], bfh[tn], c, 0, 0, 0);
                c = __builtin_amdgcn_mfma_f32_16x16x32_f16(afh[tm], bfl[tn], c, 0, 0, 0);
                acc[tm][tn] = c;
            }
    }

    __syncthreads();
    float* bins = (float*)LDS;
    #pragma unroll
    for (int i = 0; i < 16; ++i) bins[tid + (i << 8)] = 0.f;
    __syncthreads();
    float* wb = bins + (wv << 10);
    #pragma unroll
    for (int tm = 0; tm < 4; ++tm)
        #pragma unroll
        for (int tn = 0; tn < 4; ++tn) {
            int row0 = m0 + wr + tm*16 + fq*4;
            int col  = n0 + wc + tn*16 + fr;
            #pragma unroll
            for (int r = 0; r < 4; ++r) {
                int tau = (row0 + r - col) & 1023;
                atomicAdd(&wb[tau], acc[tm][tn][r]);
            }
        }
    __syncthreads();
    size_t blk = (zb << 6) + (blockIdx.y << 3) + blockIdx.x;
    for (int i = tid; i < 1024; i += 256)
        PBIN[(blk << 10) + i] = (bins[i] + bins[1024 + i]) + (bins[2048 + i] + bins[3072 + i]);
}

// fused PBIN reduce + top-6 + softmax per local batch
__launch_bounds__(256)
__global__ void topk6f(const float* __restrict__ PBIN, int* __restrict__ DELAY,
                       float* __restrict__ WGT)
{
    __shared__ float v[1024];
    __shared__ float rv[256];
    __shared__ int   ri[256];
    __shared__ float wv6[6];
    __shared__ int   wi6[6];
    const int b = blockIdx.x, tid = threadIdx.x;
    #pragma unroll
    for (int k = 0; k < 4; ++k) {
        int tau = tid + (k << 8);
        const float* pp = PBIN + ((size_t)b << 16) + tau;
        float s = 0.f;
        #pragma unroll
        for (int ch = 0; ch < 64; ++ch) s += pp[ch << 10];
        v[tau] = s * (1.f / 512.f);
    }
    __syncthreads();
    for (int it = 0; it < 6; ++it) {
        float best = v[tid]; int bi = tid;
        #pragma unroll
        for (int k = 1; k < 4; ++k) {
            int i = tid + (k << 8);
            float xv = v[i];
            if (xv > best) { best = xv; bi = i; }
        }
        rv[tid] = best; ri[tid] = bi;
        __syncthreads();
        for (int s = 128; s > 0; s >>= 1) {
            if (tid < s) {
                if (rv[tid+s] > rv[tid] || (rv[tid+s] == rv[tid] && ri[tid+s] < ri[tid])) {
                    rv[tid] = rv[tid+s]; ri[tid] = ri[tid+s];
                }
            }
            __syncthreads();
        }
        if (tid == 0) { wv6[it] = rv[0]; wi6[it] = ri[0]; v[ri[0]] = -1e30f; }
        __syncthreads();
    }
    if (tid == 0) {
        float mx = wv6[0], s = 0.f, e[6];
        #pragma unroll
        for (int i = 0; i < 6; ++i) { e[i] = expf(wv6[i] - mx); s += e[i]; }
        #pragma unroll
        for (int i = 0; i < 6; ++i) { WGT[b*6+i] = e[i]/s; DELAY[b*6+i] = wi6[i]; }
    }
}

// gather from Vh (ld 512) -> SG fp16
__launch_bounds__(256)
__global__ void gather6v(const ushortb* __restrict__ Vh, const int* __restrict__ DELAY,
                         const float* __restrict__ WGT, ushortb* __restrict__ SG)
{
    int idx = blockIdx.x * 256 + threadIdx.x;     // TG*128 threads
    int d0 = (idx & 127) << 2, bt = idx >> 7, t = bt & 1023, b = bt >> 10;
    const ushortb* Vb = Vh + ((size_t)b << 19);
    float a0=0,a1=0,a2=0,a3=0;
    #pragma unroll
    for (int i = 0; i < 6; ++i) {
        int s = (t + DELAY[b*6+i]) & 1023;
        float w = WGT[b*6+i];
        uint2 hv = *(const uint2*)(Vb + (s << 9) + d0);
        a0 += w * h2f((ushortb)(hv.x & 0xFFFFu));
        a1 += w * h2f((ushortb)(hv.x >> 16));
        a2 += w * h2f((ushortb)(hv.y & 0xFFFFu));
        a3 += w * h2f((ushortb)(hv.y >> 16));
    }
    uint2 op;
    op.x = (unsigned)f2h(a0) | ((unsigned)f2h(a1) << 16);
    op.y = (unsigned)f2h(a2) | ((unsigned)f2h(a3) << 16);
    *(uint2*)(SG + ((size_t)bt << 9) + d0) = op;
}

// series_decomp pair->pair, 4 d/thread; TTs trend rows (slot: t>=511 -> t-511, t==0 -> 513)
__launch_bounds__(256)
__global__ void decomp512v(const ushortb* __restrict__ Xh, const ushortb* __restrict__ Xl,
                           ushortb* __restrict__ Sh, ushortb* __restrict__ Sl,
                           float* __restrict__ TTs, int tmode)
{
    int idx = blockIdx.x * 256 + threadIdx.x;   // TG*128
    int d0 = (idx & 127) << 2, bt = idx >> 7, t = bt & 1023;
    int base = bt - t;
    float s0=0,s1=0,s2=0,s3=0;
    #pragma unroll
    for (int w = -12; w <= 12; ++w) {
        int tt = t + w; tt = tt < 0 ? 0 : (tt > 1023 ? 1023 : tt);
        size_t ro = ((size_t)(base + tt) << 9) + d0;
        uint2 hv = *(const uint2*)(Xh + ro);
        uint2 lv = *(const uint2*)(Xl + ro);
        s0 += h2f((ushortb)(hv.x & 0xFFFFu)) + h2f((ushortb)(lv.x & 0xFFFFu));
        s1 += h2f((ushortb)(hv.x >> 16))     + h2f((ushortb)(lv.x >> 16));
        s2 += h2f((ushortb)(hv.y & 0xFFFFu)) + h2f((ushortb)(lv.y & 0xFFFFu));
        s3 += h2f((ushortb)(hv.y >> 16))     + h2f((ushortb)(lv.y >> 16));
    }
    float m0 = s0*(1.f/25.f), m1 = s1*(1.f/25.f), m2 = s2*(1.f/25.f), m3 = s3*(1.f/25.f);
    size_t co = ((size_t)bt << 9) + d0;
    uint2 chv = *(const uint2*)(Xh + co);
    uint2 clv = *(const uint2*)(Xl + co);
    float v0 = h2f((ushortb)(chv.x & 0xFFFFu)) + h2f((ushortb)(clv.x & 0xFFFFu)) - m0;
    float v1 = h2f((ushortb)(chv.x >> 16))     + h2f((ushortb)(clv.x >> 16))     - m1;
    float v2 = h2f((ushortb)(chv.y & 0xFFFFu)) + h2f((ushortb)(clv.y & 0xFFFFu)) - m2;
    float v3 = h2f((ushortb)(chv.y >> 16))     + h2f((ushortb)(clv.y >> 16))     - m3;
    ushortb h0=f2h(v0), h1=f2h(v1), h2v=f2h(v2), h3=f2h(v3);
    uint2 hp, lp;
    hp.x = (unsigned)h0 | ((unsigned)h1 << 16); hp.y = (unsigned)h2v | ((unsigned)h3 << 16);
    lp.x = (unsigned)f2h(v0-h2f(h0)) | ((unsigned)f2h(v1-h2f(h1)) << 16);
    lp.y = (unsigned)f2h(v2-h2f(h2v)) | ((unsigned)f2h(v3-h2f(h3)) << 16);
    *(uint2*)(Sh + co) = hp; *(uint2*)(Sl + co) = lp;
    if (tmode) {
        int slot = (t >= 511) ? (t - 511) : (t == 0 ? 513 : -1);
        if (slot >= 0) {
            int b = bt >> 10;
            float* tp = TTs + (size_t)b * 263168 + ((size_t)slot << 9) + d0;
            if (tmode == 1) { tp[0]=m0; tp[1]=m1; tp[2]=m2; tp[3]=m3; }
            else            { tp[0]+=m0; tp[1]+=m1; tp[2]+=m2; tp[3]+=m3; }
        }
    }
}

// per-token LN, pair in -> pair out
__launch_bounds__(256)
__global__ void ln_rows(const ushortb* __restrict__ Xh, const ushortb* __restrict__ Xl,
                        const float* __restrict__ w, const float* __restrict__ bias,
                        ushortb* __restrict__ Yh, ushortb* __restrict__ Yl)
{
    __shared__ float r1[256], r2[256];
    const int row = blockIdx.x, tid = threadIdx.x;
    size_t ro = (size_t)row * 512;
    float x0 = h2f(Xh[ro + tid]) + h2f(Xl[ro + tid]);
    float x1 = h2f(Xh[ro + tid + 256]) + h2f(Xl[ro + tid + 256]);
    r1[tid] = x0 + x1; r2[tid] = x0*x0 + x1*x1;
    __syncthreads();
    for (int s = 128; s > 0; s >>= 1) {
        if (tid < s) { r1[tid] += r1[tid+s]; r2[tid] += r2[tid+s]; }
        __syncthreads();
    }
    float mu = r1[0] * (1.f/512.f);
    float var = r2[0] * (1.f/512.f) - mu*mu;
    float rstd = rsqrtf(var + 1e-5f);
    float v0 = (x0 - mu) * rstd * w[tid]     + bias[tid];
    float v1 = (x1 - mu) * rstd * w[tid+256] + bias[tid+256];
    ushortb h0 = f2h(v0), h1 = f2h(v1);
    Yh[ro + tid] = h0;       Yl[ro + tid] = f2h(v0 - h2f(h0));
    Yh[ro + tid + 256] = h1; Yl[ro + tid + 256] = f2h(v1 - h2f(h1));
}

// column-mean partials from pair
__launch_bounds__(256)
__global__ void colmean_p(const ushortb* __restrict__ Yh, const ushortb* __restrict__ Yl,
                          float* __restrict__ PC)
{
    int i = blockIdx.x * 256 + threadIdx.x;   // G*4096
    int b = i >> 12, r = i & 4095, d = r >> 3, c = r & 7;
    size_t o = ((size_t)b << 19) + ((size_t)(c << 7) << 9) + d;
    float s = 0.f;
    for (int t = 0; t < 128; ++t) { size_t oo = o + ((size_t)t << 9); s += h2f(Yh[oo]) + h2f(Yl[oo]); }
    PC[i] = s * (1.f/1024.f);
}

// Z = Y - colmean, pair -> pair
__launch_bounds__(256)
__global__ void submean_s(const ushortb* __restrict__ Yh, const ushortb* __restrict__ Yl,
                          const float* __restrict__ PC,
                          ushortb* __restrict__ Zh, ushortb* __restrict__ Zl)
{
    int idx = blockIdx.x * 256 + threadIdx.x;
    int d = idx & 511, b = idx >> 19;
    const float* pc = PC + ((size_t)b << 12) + (d << 3);
    float m = ((pc[0]+pc[1])+(pc[2]+pc[3]))+((pc[4]+pc[5])+(pc[6]+pc[7]));
    float v = h2f(Yh[idx]) + h2f(Yl[idx]) - m;
    ushortb h = f2h(v);
    Zh[idx] = h; Zl[idx] = f2h(v - h2f(h));
}

// embedding -> pair
__launch_bounds__(256)
__global__ void embed_es(const float* __restrict__ x, const float* __restrict__ mark,
                         const float* __restrict__ Wtok, const float* __restrict__ Wtem,
                         ushortb* __restrict__ Oh, ushortb* __restrict__ Ol)
{
    int idx = blockIdx.x * 256 + threadIdx.x;
    int d = idx & 511, bt = idx >> 9, t = bt & 1023, b = bt >> 10;
    float acc = 0.f;
    #pragma unroll
    for (int j = 0; j < 3; ++j) {
        int tt = (t + 1023 + j) & 1023;
        const float* xr = x + (size_t)(b*1024 + tt)*7;
        #pragma unroll
        for (int c = 0; c < 7; ++c)
            acc += xr[c] * Wtok[(j*7+c)*512 + d];
    }
    const float* mr = mark + (size_t)bt*4;
    #pragma unroll
    for (int m = 0; m < 4; ++m) acc += mr[m] * Wtem[m*512 + d];
    ushortb h = f2h(acc);
    Oh[idx] = h; Ol[idx] = f2h(acc - h2f(h));
}

__launch_bounds__(256)
__global__ void mean7(const float* __restrict__ x, float* __restrict__ M7)
{
    __shared__ float r[256];
    int bc = blockIdx.x, b = bc / 7, c = bc % 7, tid = threadIdx.x;
    float s = 0.f;
    for (int t = tid; t < 1024; t += 256) s += x[(size_t)(b*1024+t)*7 + c];
    r[tid] = s; __syncthreads();
    for (int st = 128; st > 0; st >>= 1) { if (tid < st) r[tid] += r[tid+st]; __syncthreads(); }
    if (tid == 0) M7[bc] = r[0] * (1.f/1024.f);
}

__launch_bounds__(256)
__global__ void decomp7(const float* __restrict__ x, const float* __restrict__ M7,
                        float* __restrict__ SEAS7, float* __restrict__ TREND7)
{
    int idx = blockIdx.x * 256 + threadIdx.x;  // TG*7
    int c = idx % 7, bt = idx / 7, t = bt & 1023, b = bt >> 10;
    if (t < 512) {
        int s0 = t + 512;
        float s = 0.f;
        #pragma unroll
        for (int w = -12; w <= 12; ++w) {
            int tt = s0 + w; tt = tt < 0 ? 0 : (tt > 1023 ? 1023 : tt);
            s += x[(size_t)(b*1024+tt)*7 + c];
        }
        float m = s * (1.f/25.f);
        SEAS7[idx] = x[(size_t)(b*1024+s0)*7 + c] - m;
        TREND7[idx] = m;
    } else {
        SEAS7[idx] = 0.f;
        TREND7[idx] = M7[b*7 + c];
    }
}

// fused: out = projb + TREND7 + X@projW + circ_conv3(TTs)@dec_trend_W  (rows t>=512)
__launch_bounds__(256)
__global__ void final_fused(const ushortb* __restrict__ Xh, const ushortb* __restrict__ Xl,
                            const float* __restrict__ PW, const float* __restrict__ PB,
                            const float* __restrict__ TW, const float* __restrict__ TTs,
                            const float* __restrict__ TREND7, float* __restrict__ out)
{
    __shared__ float WT[10752];   // 3*512*7
    __shared__ float WP[3584];    // 512*7
    for (int i = threadIdx.x; i < 10752; i += 256) WT[i] = TW[i];
    for (int i = threadIdx.x; i < 3584; i += 256) WP[i] = PW[i];
    __syncthreads();
    int idx = blockIdx.x * 256 + threadIdx.x;  // G*512*7
    int c = idx % 7, btt = idx / 7, tt = btt & 511, b = btt >> 9;
    int t = tt + 512;
    float acc = PB[c] + TREND7[(size_t)(b*1024 + t)*7 + c];
    size_t ro = ((size_t)(b*1024 + t) << 9);
    for (int d = 0; d < 512; ++d)
        acc += (h2f(Xh[ro + d]) + h2f(Xl[ro + d])) * WP[d*7 + c];
    for (int j = 0; j < 3; ++j) {
        int t2 = t - 1 + j;
        int slot = (t2 >= 1024) ? 513 : (t2 - 511);
        const float* r = TTs + (size_t)b * 263168 + ((size_t)slot << 9);
        const float* wj = WT + j*3584 + c;
        for (int d = 0; d < 512; ++d) acc += r[d] * wj[d*7];
    }
    out[idx] = acc;
}

// attn weight transpose+split pool (block a: 1572864 elems):
// QKh@0 (1024x512), QKl@524288, Vh@1048576, Oh@1310720
__launch_bounds__(256)
__global__ void wsplit_att(const float* __restrict__ W, ushortb* __restrict__ pool, int which)
{
    __shared__ float t[32][33];
    const int m = blockIdx.z;
    const int kb = blockIdx.y << 5, nb = blockIdx.x << 5;
    const int c = threadIdx.x & 31, rr = threadIdx.x >> 5;
    const float* Wm = W + (size_t)m * 262144;
    #pragma unroll
    for (int i = 0; i < 4; ++i)
        t[rr + i*8][c] = Wm[(size_t)(kb + rr + i*8) * 512 + nb + c];
    __syncthreads();
    const int a = (which == 0) ? (m >> 2) : (which + 1);
    const int j = (which == 0) ? (m & 3) : m;
    size_t hi, lo; bool haslo;
    if (j == 0)      { hi = 0;       lo = 524288; haslo = true; }
    else if (j == 1) { hi = 262144;  lo = 786432; haslo = true; }
    else if (j == 2) { hi = 1048576; lo = 0; haslo = false; }
    else             { hi = 1310720; lo = 0; haslo = false; }
    ushortb* pb = pool + (size_t)a * 1572864;
    #pragma unroll
    for (int i = 0; i < 4; ++i) {
        int n = nb + rr + i*8, k = kb + c;
        float v = t[c][rr + i*8];
        ushortb h = f2h(v);
        pb[hi + (size_t)n * 512 + k] = h;
        if (haslo) pb[lo + (size_t)n * 512 + k] = f2h(v - h2f(h));
    }
}

__launch_bounds__(256)
__global__ void wsplit_ff(const float* __restrict__ W, ushortb* __restrict__ dh,
                          int K, int N)
{
    __shared__ float t[32][33];
    const int m = blockIdx.z;
    const int kb = blockIdx.y << 5, nb = blockIdx.x << 5;
    const int c = threadIdx.x & 31, rr = threadIdx.x >> 5;
    const float* Wm = W + (size_t)m * K * N;
    #pragma unroll
    for (int i = 0; i < 4; ++i)
        t[rr + i*8][c] = Wm[(size_t)(kb + rr + i*8) * N + nb + c];
    __syncthreads();
    ushortb* Dh = dh + (size_t)m * 1048576;
    #pragma unroll
    for (int i = 0; i < 4; ++i) {
        int n = nb + rr + i*8, k = kb + c;
        Dh[(size_t)n * K + k] = f2h(t[c][rr + i*8]);
    }
}

__launch_bounds__(256)
__global__ void sentinel(float* __restrict__ out, int n)
{
    int i = blockIdx.x * 256 + threadIdx.x;
    if (i < n) out[i] = -54321.0f;
}

// ------------------------------------------------------------------
extern "C" void kernel_launch(void* const* d_in, const int* in_sizes, int n_in,
                              void* d_out, int out_size, void* d_ws, size_t ws_size,
                              hipStream_t stream)
{
    const float* x_enc      = (const float*)d_in[0];
    const float* x_mark_enc = (const float*)d_in[1];
    const float* x_mark_dec = (const float*)d_in[3];
    const float* W_enc_tok  = (const float*)d_in[4];
    const float* W_enc_tem  = (const float*)d_in[5];
    const float* W_dec_tok  = (const float*)d_in[6];
    const float* W_dec_tem  = (const float*)d_in[7];
    const float* enc_attn_W = (const float*)d_in[8];
    const float* enc_attn_b = (const float*)d_in[9];
    const float* enc_ff1    = (const float*)d_in[10];
    const float* enc_ff2    = (const float*)d_in[11];
    const float* enc_ln_w   = (const float*)d_in[12];
    const float* enc_ln_b   = (const float*)d_in[13];
    const float* dec_self_W = (const float*)d_in[14];
    const float* dec_self_b = (const float*)d_in[15];
    const float* dec_cross_W= (const float*)d_in[16];
    const float* dec_cross_b= (const float*)d_in[17];
    const float* dec_ff1    = (const float*)d_in[18];
    const float* dec_ff2    = (const float*)d_in[19];
    const float* dec_trend_W= (const float*)d_in[20];
    const float* dec_ln_w   = (const float*)d_in[21];
    const float* dec_ln_b   = (const float*)d_in[22];
    const float* proj_W     = (const float*)d_in[23];
    const float* proj_b     = (const float*)d_in[24];
    float* out = (float*)d_out;

    const size_t ATT_E = (size_t)4 * 1572864;
    const size_t FF_E  = (size_t)3 * 1048576;
    const size_t WBYTES = (ATT_E + 2 * FF_E) * 2 + 4096;

    auto need = [&](long g) -> size_t {
        size_t TGl = (size_t)g * 1024;
        size_t pairs = 3 * TGl * 2048;            // SA, TMP, SE pairs
        size_t qk    = TGl * 4096;                // QK pair / MID / SG
        size_t vh    = TGl * 1024;
        size_t tts   = (size_t)g * 263168 * 4;
        size_t pbin  = (size_t)g * 262144;
        size_t misc  = (size_t)g * (16384 + 28 + 28672 + 28672 + 64) + 65536;
        return WBYTES + pairs + qk + vh + tts + pbin + misc + 16384;
    };
    int G = 0;
    for (int g = 32; g >= 1; g >>= 1) if (need(g) <= ws_size) { G = g; break; }
    if (G == 0) {
        sentinel<<<(out_size + 255) / 256, 256, 0, stream>>>(out, out_size);
        return;
    }
    const int TG = G * 1024;

    char* p = (char*)d_ws;
    auto carve = [&](size_t bytes) -> char* {
        char* r = p; p += (bytes + 255) & ~(size_t)255; return r;
    };
    ushortb* ATT = (ushortb*)carve(ATT_E * 2);
    ushortb* FF1 = (ushortb*)carve(FF_E * 2);
    ushortb* FF2 = (ushortb*)carve(FF_E * 2);

    const size_t SPLB = (size_t)TG * 512 * 2;
    ushortb* SAh = (ushortb*)carve(SPLB);
    ushortb* SAl = (ushortb*)carve(SPLB);
    ushortb* TMh = (ushortb*)carve(SPLB);
    ushortb* TMl = (ushortb*)carve(SPLB);
    ushortb* SEh = (ushortb*)carve(SPLB);
    ushortb* SEl = (ushortb*)carve(SPLB);
    char* R1 = carve((size_t)TG * 4096);             // QKh+QKl pair / MID / SG
    ushortb* Vh = (ushortb*)carve((size_t)TG * 1024);
    float* TTs   = (float*)carve((size_t)G * 263168 * 4);
    float* PBIN  = (float*)carve((size_t)G * 262144);
    float* PC    = (float*)carve((size_t)G * 16384);
    float* M7    = (float*)carve((size_t)G * 28);
    float* SEAS7 = (float*)carve((size_t)G * 28672);
    float* TREND7= (float*)carve((size_t)G * 28672);
    float* WGT   = (float*)carve((size_t)G * 24);
    int*   DELAY = (int*)  carve((size_t)G * 24);

    ushortb* QKh = (ushortb*)R1;
    ushortb* QKl = QKh + (size_t)TG * 1024;
    ushortb* MIDh = (ushortb*)R1;
    ushortb* SG = QKl;        // gather output aliases dead QKl

    // ---- weight transforms ----
    wsplit_att<<<dim3(16,16,8),256,0,stream>>>(enc_attn_W, ATT, 0);
    wsplit_att<<<dim3(16,16,4),256,0,stream>>>(dec_self_W, ATT, 1);
    wsplit_att<<<dim3(16,16,4),256,0,stream>>>(dec_cross_W, ATT, 2);
    wsplit_ff<<<dim3(64,16,2),256,0,stream>>>(enc_ff1, FF1, 512, 2048);
    wsplit_ff<<<dim3(64,16,1),256,0,stream>>>(dec_ff1, FF1 + (size_t)2*1048576, 512, 2048);
    wsplit_ff<<<dim3(16,64,2),256,0,stream>>>(enc_ff2, FF2, 2048, 512);
    wsplit_ff<<<dim3(16,64,1),256,0,stream>>>(dec_ff2, FF2 + (size_t)2*1048576, 2048, 512);

    for (int g0 = 0; g0 < 32; g0 += G) {
        const float* xe  = x_enc      + (size_t)g0 * 1024 * 7;
        const float* me  = x_mark_enc + (size_t)g0 * 1024 * 4;
        const float* md  = x_mark_dec + (size_t)g0 * 1024 * 4;
        float*       outg= out        + (size_t)g0 * 512 * 7;
        const int GB = G * 8;   // TG/128

        auto corr_gather_oproj = [&](const ushortb* base, const float* bv,
                                     const ushortb* rh, const ushortb* rl) {
            gemm_corr<<<dim3(8,8,G),256,0,stream>>>(
                QKh,QKl,1024,(long)1048576, QKh+512,QKl+512,1024,(long)1048576, PBIN, 512);
            topk6f<<<G,256,0,stream>>>(PBIN, DELAY, WGT);
            gather6v<<<TG/2,256,0,stream>>>(Vh, DELAY, WGT, SG);
            gemm_h1<<<dim3(4,GB),256,0,stream>>>(SG,512, base+1310720,512, bv+1536,
                                                 rh,rl, TMh,TMl, 512, 512, 0);
        };
        auto attn_self = [&](const ushortb* xh, const ushortb* xl, int a, const float* bv) {
            const ushortb* base = ATT + (size_t)a * 1572864;
            gemm_h3<<<dim3(8,GB),256,0,stream>>>(xh,xl,512, base,base+524288,512, bv,
                                                 QKh,QKl, 1024, 512);
            gemm_h1<<<dim3(4,GB),256,0,stream>>>(xh,512, base+1048576,512, bv+1024,
                                                 nullptr,nullptr, Vh,nullptr, 512, 512, 0);
            corr_gather_oproj(base, bv, xh, xl);
        };
        auto attn_cross = [&](const ushortb* qh, const ushortb* ql,
                              const ushortb* kvh, const ushortb* kvl,
                              int a, const float* bv) {
            const ushortb* base = ATT + (size_t)a * 1572864;
            gemm_h3<<<dim3(4,GB),256,0,stream>>>(qh,ql,512, base,base+524288,512, bv,
                                                 QKh,QKl, 1024, 512);
            gemm_h3<<<dim3(4,GB),256,0,stream>>>(kvh,kvl,512, base+262144,base+786432,512, bv+512,
                                                 QKh+512,QKl+512, 1024, 512);
            gemm_h1<<<dim3(4,GB),256,0,stream>>>(kvh,512, base+1048576,512, bv+1024,
                                                 nullptr,nullptr, Vh,nullptr, 512, 512, 0);
            corr_gather_oproj(base, bv, qh, ql);
        };
        auto ffn = [&](const ushortb* xh, const ushortb* xl, int fi) {
            gemm_h1<<<dim3(16,GB),256,0,stream>>>(xh,512, FF1 + (size_t)fi*1048576,512, nullptr,
                                                  nullptr,nullptr, MIDh,nullptr, 2048, 512, 1);
            gemm_h1<<<dim3(4,GB),256,0,stream>>>(MIDh,2048, FF2 + (size_t)fi*1048576,2048, nullptr,
                                                 xh,xl, TMh,TMl, 512, 2048, 0);
        };

        // ---------------- encoder ----------------
        embed_es<<<TG*2,256,0,stream>>>(xe, me, W_enc_tok, W_enc_tem, SAh, SAl);
        for (int l = 0; l < 2; ++l) {
            attn_self(SAh, SAl, l, enc_attn_b + (size_t)l*4*512);
            decomp512v<<<TG/2,256,0,stream>>>(TMh, TMl, SAh, SAl, nullptr, 0);
            ffn(SAh, SAl, l);
            decomp512v<<<TG/2,256,0,stream>>>(TMh, TMl, SAh, SAl, nullptr, 0);
        }
        ln_rows<<<TG,256,0,stream>>>(SAh, SAl, enc_ln_w, enc_ln_b, TMh, TMl);
        colmean_p<<<G*16,256,0,stream>>>(TMh, TMl, PC);
        submean_s<<<TG*2,256,0,stream>>>(TMh, TMl, PC, SEh, SEl);

        // ---------------- decoder prep ----------------
        mean7<<<G*7,256,0,stream>>>(xe, M7);
        decomp7<<<G*28,256,0,stream>>>(xe, M7, SEAS7, TREND7);
        embed_es<<<TG*2,256,0,stream>>>(SEAS7, md, W_dec_tok, W_dec_tem, SAh, SAl);

        // ---------------- decoder layer ----------------
        attn_self(SAh, SAl, 2, dec_self_b);
        decomp512v<<<TG/2,256,0,stream>>>(TMh, TMl, SAh, SAl, TTs, 1);

        attn_cross(SAh, SAl, SEh, SEl, 3, dec_cross_b);
        decomp512v<<<TG/2,256,0,stream>>>(TMh, TMl, SAh, SAl, TTs, 2);

        ffn(SAh, SAl, 2);
        decomp512v<<<TG/2,256,0,stream>>>(TMh, TMl, SAh, SAl, TTs, 2);

        ln_rows<<<TG,256,0,stream>>>(SAh, SAl, dec_ln_w, dec_ln_b, TMh, TMl);
        colmean_p<<<G*16,256,0,stream>>>(TMh, TMl, PC);
        submean_s<<<TG*2,256,0,stream>>>(TMh, TMl, PC, SAh, SAl);

        final_fused<<<G*14,256,0,stream>>>(SAh, SAl, proj_W, proj_b, dec_trend_W,
                                           TTs, TREND7, outg);
    }
}